// Round 11
// baseline (1403.611 us; speedup 1.0000x reference)
//
#include <hip/hip_runtime.h>
#include <hip/hip_cooperative_groups.h>
#include <math.h>

namespace cg = cooperative_groups;

#define L_ 128
#define D_ 128
#define H_ 8
#define V_ 32000
#define NEGC 1e9f

typedef short short8 __attribute__((ext_vector_type(8)));
typedef float f32x4 __attribute__((ext_vector_type(4)));
typedef unsigned short ushort8v __attribute__((ext_vector_type(8)));

__device__ __forceinline__ unsigned short f2bf(float x) {
    unsigned int u = __float_as_uint(x);
    unsigned int r = (u + 0x7fff + ((u >> 16) & 1)) >> 16;
    return (unsigned short)r;
}

struct LoopArgs {
    float* qz;
    float* ue;
    float* exbuf;
    float* rowsum;
    float* g1;
    float* g2;
    const float* x;
    const float* T;
    const float* Tt;
    float* U2;
    float* prs;
    unsigned short* qzb;
    const unsigned short* Ebf;
    const unsigned short* Etf;
    unsigned short* A0b;
    unsigned short* A1b;
    unsigned short* A0Tb;
    unsigned short* A1Tb;
    unsigned short* Ut;
    unsigned short* Wt;
    const int* mask;
    const int* m_mask;
    const int* rowidx;
    const int* nactb;
    float* partial;   // aliases out
    float* out;
};

// ---------- one-time precompute ----------

// prep_k = frag (blocks [0,1000)) | transT ([1000,1256)) | compact (1256)
//        | colsum ([1257,1382)) — all 256 thr, independent parts.
__global__ __launch_bounds__(256) void prep_k(const float* __restrict__ E,
                                              unsigned short* __restrict__ Ebf,
                                              unsigned short* __restrict__ Etf,
                                              const float* __restrict__ T, float* __restrict__ Tt,
                                              const int* __restrict__ m_mask,
                                              int* __restrict__ rowidx, int* __restrict__ nactb,
                                              float* __restrict__ meansum) {
    __shared__ __align__(16) unsigned char psmem[8704];
    int blk = blockIdx.x;
    int t = threadIdx.x;
    if (blk < 1000) {
        unsigned short* tile = (unsigned short*)psmem;   // [32][136]
        int v0 = blk * 32;
#pragma unroll
        for (int i = 0; i < 4; ++i) {
            int idx = i * 256 + t;
            int v = idx >> 5;
            int d4 = (idx & 31) * 4;
            float4 val = *(const float4*)&E[(size_t)(v0 + v) * 128 + d4];
            tile[v * 136 + d4 + 0] = f2bf(val.x);
            tile[v * 136 + d4 + 1] = f2bf(val.y);
            tile[v * 136 + d4 + 2] = f2bf(val.z);
            tile[v * 136 + d4 + 3] = f2bf(val.w);
        }
        __syncthreads();
        {
            int fi = t >> 5;
            int l0 = (t & 31) * 2;
            int vtl = fi >> 2, s = fi & 3;
            size_t base = ((size_t)(blk * 2 + vtl) * 4 + s) * 512;
#pragma unroll
            for (int li = 0; li < 2; ++li) {
                int l = l0 + li;
                int nl = l & 15, hf = l >> 4;
                ushort8v o;
#pragma unroll
                for (int j = 0; j < 8; ++j) o[j] = tile[(vtl * 16 + nl) * 136 + s * 32 + hf * 8 + j];
                *(ushort8v*)&Ebf[base + l * 8] = o;
            }
        }
        {
            int ct = t >> 5;
            int l0 = (t & 31) * 2;
            size_t base = ((size_t)blk * 8 + ct) * 512;
#pragma unroll
            for (int li = 0; li < 2; ++li) {
                int l = l0 + li;
                int nl = l & 15, hf = l >> 4;
                ushort8v o;
#pragma unroll
                for (int j = 0; j < 8; ++j) o[j] = tile[(hf * 8 + j) * 136 + ct * 16 + nl];
                *(ushort8v*)&Etf[base + l * 8] = o;
            }
        }
    } else if (blk < 1256) {
        int tb = blk - 1000;
        for (int q = 0; q < 4; ++q) {
            int id = tb * 1024 + q * 256 + t;
            int k = id >> 17;
            int rem = id & 131071;
            int a = rem >> 10;
            int bc = rem & 1023;
            int b = bc >> 3, c = bc & 7;
            Tt[k * 131072 + b * 1024 + a * 8 + c] = T[id];
        }
    } else if (blk == 1256) {
        int* wc = (int*)psmem;   // [8]
        bool a0 = m_mask[t] != 0;
        bool a1 = m_mask[t + 256] != 0;
        unsigned long long b0 = __ballot(a0);
        unsigned long long b1 = __ballot(a1);
        int w = t >> 6, lane = t & 63;
        if (lane == 0) { wc[w] = __popcll(b0); wc[4 + w] = __popcll(b1); }
        __syncthreads();
        int base0 = 0;
        for (int i = 0; i < w; ++i) base0 += wc[i];
        int base1 = 0;
        for (int i = 0; i < 4 + w; ++i) base1 += wc[i];
        if (a0) rowidx[base0 + __popcll(b0 & ((1ull << lane) - 1))] = t;
        if (a1) rowidx[base1 + __popcll(b1 & ((1ull << lane) - 1))] = t + 256;
        if (t == 0) {
            int tot = 0;
            for (int i = 0; i < 8; ++i) tot += wc[i];
            nactb[0] = tot;
        }
    } else {
        float* red = (float*)psmem;   // [256]
        int d = t & 127, h = t >> 7;
        int v0 = (blk - 1257) * 256;
        float s = 0.f;
        for (int p = 0; p < 128; ++p)
            s += E[(size_t)(v0 + h + 2 * p) * 128 + d];
        red[t] = s;
        __syncthreads();
        if (h == 0) atomicAdd(&meansum[d], red[d] + red[128 + d]);
    }
}

// ue = select(mm, colmean, x);  qz = softmax_D(ue*keep)*keep  (+ bf16 copy)
__global__ __launch_bounds__(64) void init_k(const float* __restrict__ x, const int* __restrict__ mask,
                                             const int* __restrict__ m_mask, const float* __restrict__ meansum,
                                             float* __restrict__ ue, float* __restrict__ qz,
                                             unsigned short* __restrict__ qzb) {
    int row = blockIdx.x, t = threadIdx.x;
    float keepv = mask[row] ? 1.f : 0.f;
    bool mm = m_mask[row] != 0;
    float pre0 = meansum[t] * (1.f / 32000.f);
    float pre1 = meansum[t + 64] * (1.f / 32000.f);
    float u0 = mm ? pre0 : x[row * 128 + t];
    float u1 = mm ? pre1 : x[row * 128 + t + 64];
    ue[row * 128 + t] = u0;
    ue[row * 128 + t + 64] = u1;
    float sv0 = u0 * keepv, sv1 = u1 * keepv;
    float m = fmaxf(sv0, sv1);
    for (int off = 32; off; off >>= 1) m = fmaxf(m, __shfl_xor(m, off));
    float e0 = __expf(sv0 - m), e1 = __expf(sv1 - m);
    float s = e0 + e1;
    for (int off = 32; off; off >>= 1) s += __shfl_xor(s, off);
    float inv = keepv / s;
    float q0 = e0 * inv, q1 = e1 * inv;
    qz[row * 128 + t] = q0;
    qz[row * 128 + t + 64] = q1;
    qzb[row * 128 + t] = f2bf(q0);
    qzb[row * 128 + t + 64] = f2bf(q1);
}

// ---------- per-iteration device functions ----------

__device__ __forceinline__ void dev_uwgemm(int blk, int t, unsigned char* smem, const LoopArgs& a) {
    float* aL = (float*)smem;           // [2048]
    int by = blk >> 5;                  // 16: uw(2) x z(4) x k(2)
    int uw = by >> 3, z = (by >> 1) & 3, k = by & 1;
    int bx = blk & 31;                  // 32: mt(8) x nt(4)
    int m0 = (bx >> 2) * 16, n = (bx & 3) * 256 + t;
    const float* A = a.qz + z * 16384;
    const float* Bm = (uw ? a.Tt : a.T) + k * 131072;
    for (int idx = t; idx < 2048; idx += 256)
        aL[idx] = A[(m0 + (idx >> 7)) * 128 + (idx & 127)];
    __syncthreads();
    float acc[16];
#pragma unroll
    for (int m = 0; m < 16; ++m) acc[m] = 0.f;
    for (int kq = 0; kq < 32; ++kq) {
        float b0 = Bm[(kq * 4 + 0) * 1024 + n];
        float b1 = Bm[(kq * 4 + 1) * 1024 + n];
        float b2 = Bm[(kq * 4 + 2) * 1024 + n];
        float b3 = Bm[(kq * 4 + 3) * 1024 + n];
#pragma unroll
        for (int m = 0; m < 16; ++m) {
            const float4 aq = *(const float4*)&aL[m * 128 + kq * 4];
            acc[m] += aq.x * b0 + aq.y * b1 + aq.z * b2 + aq.w * b3;
        }
    }
    if (uw == 0) {
        float* Cm = a.U2 + (z * 2 + k) * 131072;
#pragma unroll
        for (int m = 0; m < 16; ++m)
            Cm[(m0 + m) * 1024 + n] = acc[m];
    }
    int bb = n >> 3, cc = n & 7;
    ushort8v p0, p1;
#pragma unroll
    for (int m = 0; m < 8; ++m) { p0[m] = f2bf(acc[m]); p1[m] = f2bf(acc[8 + m]); }
    unsigned short* To = (uw ? a.Wt : a.Ut) + ((size_t)(z * 2 + k) * 128 + bb) * 1024 + cc * 128 + m0;
    *(ushort8v*)&To[0] = p0;
    *(ushort8v*)&To[8] = p1;
}

// pxe (round-5 structure, NO atomics): 16 rows x 640 v per job; 4 waves x 5
// chunks, double-buffered Ebf; XCD swizzle preserved (block = job mod grid,
// grid % 8 == 0).
__device__ __forceinline__ void dev_pxe(int bid, int t, unsigned char* smem, const LoopArgs& a) {
    int nact = a.nactb[0];
    int xcd = bid & 7, idx = bid >> 3;    // idx 0..223
    int g = xcd + 8 * (idx >> 5);         // v-group 0..55 (g>=50 dead)
    int bx = idx & 31;                    // row-tile
    int r0 = bx * 16;
    if (g >= 50 || r0 >= nact) return;
    unsigned short* Pl = (unsigned short*)smem;               // [4][2][576]
    float* slab = (float*)(smem + 9216);                      // [4][2080]
    float* rsW  = (float*)(smem + 9216 + 33280);              // [4][16]
    int w = t >> 6, lane = t & 63;
    int nloc = lane & 15, half = lane >> 4;
    int rA = r0 + nloc;
    bool actA = rA < nact;
    int rowA = actA ? a.rowidx[rA] : 0;
    short8 zero8 = (short8){0, 0, 0, 0, 0, 0, 0, 0};
    short8 afr[4];                         // qz frag (idx=z-row, k=d)
#pragma unroll
    for (int s = 0; s < 4; ++s) {
        short8 v = *(const short8*)&a.qzb[rowA * 128 + s * 32 + half * 8];
        afr[s] = actA ? v : zero8;
    }
    const int kc0 = g * 20 + w * 5;        // this wave's 5 chunks
    short8 ebb[2][8];                      // double-buffered Ebf frags
#pragma unroll
    for (int f = 0; f < 8; ++f)
        ebb[0][f] = *(const short8*)&a.Ebf[((size_t)(kc0 * 8 + f)) * 512 + lane * 8];
    f32x4 acc2[8];
#pragma unroll
    for (int ct = 0; ct < 8; ++ct) acc2[ct] = (f32x4){0.f, 0.f, 0.f, 0.f};
    float rsl = 0.f;
#pragma unroll
    for (int step = 0; step < 5; ++step) {
        const int p = step & 1;
        const int kc = kc0 + step;
        short8 et[8];                      // current Etf frags (issued early)
#pragma unroll
        for (int f = 0; f < 8; ++f)
            et[f] = *(const short8*)&a.Etf[((size_t)(kc * 8 + f)) * 512 + lane * 8];
        if (step < 4) {                    // prefetch next Ebf frags
#pragma unroll
            for (int f = 0; f < 8; ++f)
                ebb[p ^ 1][f] = *(const short8*)&a.Ebf[((size_t)((kc + 1) * 8 + f)) * 512 + lane * 8];
        }
        // MFMA1 (swapped): D[v_local = half*4+reg][z = nloc], 2 chains
        f32x4 p0 = (f32x4){0.f, 0.f, 0.f, 0.f};
        f32x4 p1 = (f32x4){0.f, 0.f, 0.f, 0.f};
#pragma unroll
        for (int s = 0; s < 4; ++s) {
            p0 = __builtin_amdgcn_mfma_f32_16x16x32_bf16(ebb[p][s], afr[s], p0, 0, 0, 0);
            p1 = __builtin_amdgcn_mfma_f32_16x16x32_bf16(ebb[p][4 + s], afr[s], p1, 0, 0, 0);
        }
        unsigned short* pw = Pl + (w * 2 + p) * 576;
        {
            float e0 = __expf(p0[0]), e1 = __expf(p0[1]), e2 = __expf(p0[2]), e3 = __expf(p0[3]);
            rsl += (e0 + e1) + (e2 + e3);
            uint2 pk = {(unsigned)f2bf(e0) | ((unsigned)f2bf(e1) << 16),
                        (unsigned)f2bf(e2) | ((unsigned)f2bf(e3) << 16)};
            *(uint2*)&pw[nloc * 36 + half * 4] = pk;
        }
        {
            float e0 = __expf(p1[0]), e1 = __expf(p1[1]), e2 = __expf(p1[2]), e3 = __expf(p1[3]);
            rsl += (e0 + e1) + (e2 + e3);
            uint2 pk = {(unsigned)f2bf(e0) | ((unsigned)f2bf(e1) << 16),
                        (unsigned)f2bf(e2) | ((unsigned)f2bf(e3) << 16)};
            *(uint2*)&pw[nloc * 36 + 16 + half * 4] = pk;
        }
        short8 a2 = *(const short8*)&pw[nloc * 36 + half * 8];
#pragma unroll
        for (int ct = 0; ct < 8; ++ct)
            acc2[ct] = __builtin_amdgcn_mfma_f32_16x16x32_bf16(a2, et[ct], acc2[ct], 0, 0, 0);
    }
    rsl += __shfl_xor(rsl, 16);
    rsl += __shfl_xor(rsl, 32);
    if (lane < 16) rsW[w * 16 + nloc] = rsl;
#pragma unroll
    for (int ct = 0; ct < 8; ++ct)
#pragma unroll
        for (int reg = 0; reg < 4; ++reg)
            slab[w * 2080 + (half * 4 + reg) * 130 + ct * 16 + nloc] = acc2[ct][reg];
    __syncthreads();
    float* pb = a.partial + (size_t)g * 65536;
    for (int i = t; i < 2048; i += 256) {
        int row = i >> 7, col = i & 127;
        int rr = r0 + row;
        if (rr < nact)
            pb[rr * 128 + col] = slab[row * 130 + col] + slab[2080 + row * 130 + col]
                               + slab[4160 + row * 130 + col] + slab[6240 + row * 130 + col];
    }
    if (t < 16) {
        int rr = r0 + t;
        if (rr < nact)
            a.prs[g * 512 + rr] = rsW[t] + rsW[16 + t] + rsW[32 + t] + rsW[48 + t];
    }
}

__device__ __forceinline__ void dev_qhnF(int blk, int t, unsigned char* smem, const LoopArgs& a) {
    float* As = (float*)smem;                     // [2][16][36]
    float* Bs = (float*)(smem + 4608);            // [128][36]
    int* maskL = (int*)(smem + 4608 + 18432);     // [128]
    int z = blk >> 6, c = (blk >> 3) & 7, iq = blk & 7;
    int i0 = iq * 16;
    int tj = t & 15, ti = t >> 4;
    int i = i0 + ti;
    if (t < 128) maskL[t] = a.mask[z * 128 + t];
    float acc0[8], acc1[8];
#pragma unroll
    for (int jj = 0; jj < 8; ++jj) { acc0[jj] = 0.f; acc1[jj] = 0.f; }
    const float* U2z = a.U2 + (size_t)z * 262144;
    const float* qzz = a.qz + z * 16384;
    for (int kb = 0; kb < 4; ++kb) {
        int b0 = kb * 32;
        __syncthreads();
        for (int e = t; e < 1024; e += 256) {
            int k = e >> 9, r = e & 511, ii = r >> 5, b = r & 31;
            As[(k * 16 + ii) * 36 + b] = U2z[k * 131072 + (i0 + ii) * 1024 + (b0 + b) * 8 + c];
        }
        for (int f = t; f < 1024; f += 256) {
            int j = f >> 3, b4 = f & 7;
            int slot = b4 ^ ((j >> 3) & 7);
            *(float4*)&Bs[j * 36 + slot * 4] = *(const float4*)&qzz[j * 128 + b0 + b4 * 4];
        }
        __syncthreads();
#pragma unroll
        for (int b4 = 0; b4 < 8; ++b4) {
            float4 a0 = *(const float4*)&As[(0 * 16 + ti) * 36 + b4 * 4];
            float4 a1 = *(const float4*)&As[(1 * 16 + ti) * 36 + b4 * 4];
#pragma unroll
            for (int jj = 0; jj < 8; ++jj) {
                int j = tj * 8 + jj;
                int slot = b4 ^ ((j >> 3) & 7);
                float4 bq = *(const float4*)&Bs[j * 36 + slot * 4];
                acc0[jj] += a0.x * bq.x;
                acc0[jj] += a0.y * bq.y;
                acc0[jj] += a0.z * bq.z;
                acc0[jj] += a0.w * bq.w;
                acc1[jj] += a1.x * bq.x;
                acc1[jj] += a1.y * bq.y;
                acc1[jj] += a1.z * bq.z;
                acc1[jj] += a1.w * bq.w;
            }
        }
    }
    bool vi = maskL[i] != 0;
    float fv[8];
#pragma unroll
    for (int jj = 0; jj < 8; ++jj) {
        int j2 = tj * 8 + jj;
        float F = (j2 > i) ? acc0[jj] : acc1[jj];
        if (j2 == i) F -= NEGC;
        if (!vi || maskL[j2] == 0) F = -NEGC;
        fv[jj] = F;
    }
    float mval = fv[0];
#pragma unroll
    for (int jj = 1; jj < 8; ++jj) mval = fmaxf(mval, fv[jj]);
    for (int off = 1; off < 16; off <<= 1) mval = fmaxf(mval, __shfl_xor(mval, off));
    float ssum = 0.f;
#pragma unroll
    for (int jj = 0; jj < 8; ++jj) ssum += __expf(fv[jj] - mval);
    for (int off = 1; off < 16; off <<= 1) ssum += __shfl_xor(ssum, off);
    float inv = 1.f / ssum;
    size_t base = (size_t)(z * 8 + c) * 16384;
    ushort8v v0, v1;
    unsigned short bvv[8];
#pragma unroll
    for (int jj = 0; jj < 8; ++jj) {
        int j2 = tj * 8 + jj;
        float val = __expf(fv[jj] - mval) * inv;
        unsigned short bv = f2bf(val);
        bvv[jj] = bv;
        v0[jj] = (j2 > i) ? bv : (unsigned short)0;
        v1[jj] = (j2 < i) ? bv : (unsigned short)0;
    }
    *(ushort8v*)&a.A0b[base + i * 128 + tj * 8] = v0;
    *(ushort8v*)&a.A1b[base + i * 128 + tj * 8] = v1;
#pragma unroll
    for (int jj = 0; jj < 8; ++jj) {
        int j2 = tj * 8 + jj;
        a.A0Tb[base + j2 * 128 + i] = (i < j2) ? bvv[jj] : (unsigned short)0;
        a.A1Tb[base + j2 * 128 + i] = (i > j2) ? bvv[jj] : (unsigned short)0;
    }
}

__device__ __forceinline__ void dev_reduce(int blk, int t, const LoopArgs& a) {
    int nact = a.nactb[0];
    int idx = blk * 256 + t;   // 0..65535
    int rr = idx >> 7, col = idx & 127;
    if (rr >= nact) return;
    float s = 0.f;
#pragma unroll 10
    for (int g = 0; g < 50; ++g)
        s += a.partial[(size_t)g * 65536 + rr * 128 + col];
    int row = a.rowidx[rr];
    a.exbuf[row * 128 + col] = s;
    if (col == 0) {
        float ts = 0.f;
#pragma unroll 10
        for (int g = 0; g < 50; ++g) ts += a.prs[g * 512 + rr];
        a.rowsum[row] = ts;
    }
}

// gkern unit = mode*256 + bx, 64-lane granularity.
__device__ __forceinline__ void dev_gkern(int unit, int lane, const LoopArgs& a) {
    int mode = unit >> 8;
    int bx = unit & 255;
    int z = bx >> 6, it = (bx >> 3) & 7, at = bx & 7;
    int nloc = lane & 15, half = lane >> 4;
    int i0 = it * 16, a0 = at * 16;
    const unsigned short* Am0 = (mode ? a.A0Tb : a.A0b) + (size_t)z * 131072;
    const unsigned short* Am1 = (mode ? a.A1Tb : a.A1b) + (size_t)z * 131072;
    const unsigned short* Bt = mode ? a.Ut : a.Wt;
    const unsigned short* B0 = Bt + (size_t)(z * 2 + 0) * 131072 + (size_t)(a0 + nloc) * 1024;
    const unsigned short* B1 = Bt + (size_t)(z * 2 + 1) * 131072 + (size_t)(a0 + nloc) * 1024;
    const unsigned short* Ar0 = Am0 + (size_t)(i0 + nloc) * 128;
    const unsigned short* Ar1 = Am1 + (size_t)(i0 + nloc) * 128;
    f32x4 acc = (f32x4){0.f, 0.f, 0.f, 0.f};
#pragma unroll
    for (int c = 0; c < 8; ++c) {
#pragma unroll
        for (int sb = 0; sb < 4; ++sb) {
            int s0 = sb * 32 + half * 8;
            short8 av0 = *(const short8*)&Ar0[c * 16384 + s0];
            short8 bv0 = *(const short8*)&B0[c * 128 + s0];
            acc = __builtin_amdgcn_mfma_f32_16x16x32_bf16(av0, bv0, acc, 0, 0, 0);
            short8 av1 = *(const short8*)&Ar1[c * 16384 + s0];
            short8 bv1 = *(const short8*)&B1[c * 128 + s0];
            acc = __builtin_amdgcn_mfma_f32_16x16x32_bf16(av1, bv1, acc, 0, 0, 0);
        }
    }
    float* G = mode ? a.g2 : a.g1;
#pragma unroll
    for (int reg = 0; reg < 4; ++reg)
        G[(z * 128 + i0 + half * 4 + reg) * 128 + a0 + nloc] = acc[reg];
}

// zupd: one 64-lane wave per row.
__device__ __forceinline__ void dev_zupd(int row, int t, const LoopArgs& a, int useEx) {
    float keepv = a.mask[row] ? 1.f : 0.f;
    int b = row * 128;
    float u0, u1;
    if (useEx) {
        if (a.m_mask[row] != 0) {
            float rsv = a.rowsum[row];
            u0 = a.exbuf[b + t] / rsv;
            u1 = a.exbuf[b + t + 64] / rsv;
        } else {
            u0 = a.x[b + t];
            u1 = a.x[b + t + 64];
        }
    } else {
        u0 = a.ue[b + t];
        u1 = a.ue[b + t + 64];
    }
    float v0 = u0 + a.g1[b + t] + a.g2[b + t];
    float v1 = u1 + a.g1[b + t + 64] + a.g2[b + t + 64];
    float m = fmaxf(v0, v1);
    for (int off = 32; off; off >>= 1) m = fmaxf(m, __shfl_xor(m, off));
    float e0 = __expf(v0 - m), e1 = __expf(v1 - m);
    float s = e0 + e1;
    for (int off = 32; off; off >>= 1) s += __shfl_xor(s, off);
    float inv = keepv / s;
    float q0 = e0 * inv, q1 = e1 * inv;
    a.qz[b + t] = q0;
    a.qz[b + t + 64] = q1;
    a.qzb[b + t] = f2bf(q0);
    a.qzb[b + t + 64] = f2bf(q1);
}

// msgx: job = by*8 + bx of the old (8,125) grid.
__device__ __forceinline__ void dev_msgx(int job, int t, const LoopArgs& a) {
    int w = t >> 6, lane = t & 63;
    int nloc = lane & 15, half = lane >> 4;
    int rt0 = (job & 7) * 64;
    int cb0 = (job >> 3) * 256 + w * 64;
    short8 afr[4][4];
#pragma unroll
    for (int r = 0; r < 4; ++r)
#pragma unroll
        for (int s = 0; s < 4; ++s)
            afr[r][s] = *(const short8*)&a.qzb[(rt0 + r * 16 + nloc) * 128 + s * 32 + half * 8];
    f32x4 acc[4][4];
#pragma unroll
    for (int r = 0; r < 4; ++r)
#pragma unroll
        for (int ct = 0; ct < 4; ++ct)
            acc[r][ct] = (f32x4){0.f, 0.f, 0.f, 0.f};
#pragma unroll
    for (int ct = 0; ct < 4; ++ct) {
#pragma unroll
        for (int s = 0; s < 4; ++s) {
            short8 bfr = *(const short8*)&a.Ebf[(((size_t)(cb0 >> 4) + ct) * 4 + s) * 512 + lane * 8];
#pragma unroll
            for (int r = 0; r < 4; ++r)
                acc[r][ct] = __builtin_amdgcn_mfma_f32_16x16x32_bf16(afr[r][s], bfr, acc[r][ct], 0, 0, 0);
        }
    }
#pragma unroll
    for (int r = 0; r < 4; ++r)
#pragma unroll
        for (int ct = 0; ct < 4; ++ct) {
            int col = cb0 + ct * 16 + nloc;
#pragma unroll
            for (int reg = 0; reg < 4; ++reg) {
                int row = rt0 + r * 16 + half * 4 + reg;
                a.out[(size_t)row * V_ + col] = acc[r][ct][reg];
            }
        }
}

// ---------- persistent cooperative loop kernel ----------
// 512 blocks x 256 thr (__launch_bounds__(256,2): VGPR<=256, LDS 42.75KB ->
// >=2 blocks/CU, all 512 co-resident). Grid-stride job sweeps + grid.sync
// between phases replace 16 dispatch boundaries.
__global__ __launch_bounds__(256, 2) void loop_k(LoopArgs a) {
    cg::grid_group grid = cg::this_grid();
    __shared__ __align__(16) unsigned char smem[42752];
    int t = threadIdx.x;
    int w = t >> 6, lane = t & 63;
    const int G = gridDim.x;
    for (int it = 0; it < 4; ++it) {
        int nA = it ? 2304 : 512;
        for (int job = blockIdx.x; job < nA; job += G) {
            __syncthreads();
            if (job < 512) dev_uwgemm(job, t, smem, a);
            else dev_pxe(job - 512, t, smem, a);
        }
        grid.sync();
        int nB = it ? 512 : 256;
        for (int job = blockIdx.x; job < nB; job += G) {
            __syncthreads();
            if (job < 256) dev_qhnF(job, t, smem, a);
            else dev_reduce(job - 256, t, a);
        }
        grid.sync();
        for (int jb = blockIdx.x; jb < 128; jb += G)
            dev_gkern(jb * 4 + w, lane, a);
        grid.sync();
        for (int jb = blockIdx.x; jb < 128; jb += G)
            dev_zupd(jb * 4 + w, lane, a, it ? 1 : 0);
        grid.sync();
    }
    for (int job = blockIdx.x; job < 1000; job += G)
        dev_msgx(job, t, a);
}

// ---------- fallback wrappers (if cooperative launch unavailable) ----------
__global__ __launch_bounds__(256) void fA_k(LoopArgs a, int it) {
    __shared__ __align__(16) unsigned char smem[42752];
    int nA = it ? 2304 : 512;
    for (int job = blockIdx.x; job < nA; job += gridDim.x) {
        __syncthreads();
        if (job < 512) dev_uwgemm(job, threadIdx.x, smem, a);
        else dev_pxe(job - 512, threadIdx.x, smem, a);
    }
}
__global__ __launch_bounds__(256) void fB_k(LoopArgs a, int it) {
    __shared__ __align__(16) unsigned char smem[42752];
    int nB = it ? 512 : 256;
    for (int job = blockIdx.x; job < nB; job += gridDim.x) {
        __syncthreads();
        if (job < 256) dev_qhnF(job, threadIdx.x, smem, a);
        else dev_reduce(job - 256, threadIdx.x, a);
    }
}
__global__ __launch_bounds__(256) void fG_k(LoopArgs a) {
    int w = threadIdx.x >> 6, lane = threadIdx.x & 63;
    for (int jb = blockIdx.x; jb < 128; jb += gridDim.x)
        dev_gkern(jb * 4 + w, lane, a);
}
__global__ __launch_bounds__(256) void fZ_k(LoopArgs a, int it) {
    int w = threadIdx.x >> 6, lane = threadIdx.x & 63;
    for (int jb = blockIdx.x; jb < 128; jb += gridDim.x)
        dev_zupd(jb * 4 + w, lane, a, it ? 1 : 0);
}
__global__ __launch_bounds__(256) void fM_k(LoopArgs a) {
    for (int job = blockIdx.x; job < 1000; job += gridDim.x)
        dev_msgx(job, threadIdx.x, a);
}

extern "C" void kernel_launch(void* const* d_in, const int* in_sizes, int n_in,
                              void* d_out, int out_size, void* d_ws, size_t ws_size,
                              hipStream_t stream) {
    const float* x     = (const float*)d_in[0];   // [B,L,D]
    const int*   mask  = (const int*)d_in[1];     // [B,L]
    const float* E     = (const float*)d_in[2];   // [V,D]
    const int*   mmask = (const int*)d_in[3];     // [B,L]
    const float* T     = (const float*)d_in[4];   // [2,D,D,H]
    float* out = (float*)d_out;                   // [B,L,V]

    float* w = (float*)d_ws;
    float* meansum = w;                 // 128
    float* ue      = w + 128;           // 65536
    float* qz      = ue + 65536;        // 65536
    float* exbuf   = qz + 65536;        // 65536
    float* rowsum  = exbuf + 65536;     // 512
    float* g1      = rowsum + 512;      // 65536
    float* g2      = g1 + 65536;        // 65536
    float* Tt      = g2 + 65536;        // 262144
    float* U2      = Tt + 262144;       // 1048576 (fp32, qhnF input)
    float* prs     = U2 + 1048576;      // 25600 (partial row-sums [50][512])
    unsigned short* qzb  = (unsigned short*)(prs + 25600);   // 65536
    unsigned short* Ebf  = qzb + 65536;                      // 4,096,000
    unsigned short* Etf  = Ebf + 4096000;                    // 4,096,000
    unsigned short* A0b  = Etf + 4096000;                    // 524288
    unsigned short* A1b  = A0b + 524288;                     // 524288
    unsigned short* A0Tb = A1b + 524288;                     // 524288
    unsigned short* A1Tb = A0Tb + 524288;                    // 524288
    unsigned short* Ut   = A1Tb + 524288;                    // 1048576
    unsigned short* Wt   = Ut + 1048576;                     // 1048576
    int* rowidx = (int*)(Wt + 1048576);                      // 512
    int* nactb  = rowidx + 512;                              // 16

    // partial exbuf slabs [50][512][128] f32 = 13.1 MB, live only between
    // phase A and phase B -> reuse d_out (dead until final msgx phase).
    float* partial = out;

    hipMemsetAsync(meansum, 0, 128 * sizeof(float), stream);
    prep_k<<<1382, 256, 0, stream>>>(E, Ebf, Etf, T, Tt, mmask, rowidx, nactb, meansum);
    init_k<<<512, 64, 0, stream>>>(x, mask, mmask, meansum, ue, qz, qzb);

    LoopArgs args;
    args.qz = qz; args.ue = ue; args.exbuf = exbuf; args.rowsum = rowsum;
    args.g1 = g1; args.g2 = g2; args.x = x; args.T = T; args.Tt = Tt;
    args.U2 = U2; args.prs = prs; args.qzb = qzb; args.Ebf = Ebf; args.Etf = Etf;
    args.A0b = A0b; args.A1b = A1b; args.A0Tb = A0Tb; args.A1Tb = A1Tb;
    args.Ut = Ut; args.Wt = Wt; args.mask = mask; args.m_mask = mmask;
    args.rowidx = rowidx; args.nactb = nactb; args.partial = partial; args.out = out;

    void* kp[] = { (void*)&args };
    hipError_t err = hipLaunchCooperativeKernel((const void*)loop_k, dim3(512), dim3(256),
                                                kp, 0, stream);
    if (err != hipSuccess) {
        // fallback: per-phase dispatches (same device code, normal launches)
        for (int it = 0; it < 4; ++it) {
            fA_k<<<it ? 2304 : 512, 256, 0, stream>>>(args, it);
            fB_k<<<it ? 512 : 256, 256, 0, stream>>>(args, it);
            fG_k<<<128, 256, 0, stream>>>(args);
            fZ_k<<<128, 256, 0, stream>>>(args, it);
        }
        fM_k<<<1000, 256, 0, stream>>>(args);
    }
}

// Round 12
// 474.438 us; speedup vs baseline: 2.9585x; 2.9585x over previous
//
#include <hip/hip_runtime.h>
#include <math.h>

#define L_ 128
#define D_ 128
#define H_ 8
#define V_ 32000
#define NEGC 1e9f

typedef short short8 __attribute__((ext_vector_type(8)));
typedef float f32x4 __attribute__((ext_vector_type(4)));
typedef unsigned short ushort8v __attribute__((ext_vector_type(8)));

__device__ __forceinline__ unsigned short f2bf(float x) {
    unsigned int u = __float_as_uint(x);
    unsigned int r = (u + 0x7fff + ((u >> 16) & 1)) >> 16;
    return (unsigned short)r;
}

// ---------- one-time precompute ----------

// prep_k = frag (blocks [0,1000)) | transT ([1000,1256)) | compact (1256)
//        | colsum ([1257,1382)) — all 256 thr, independent parts.
__global__ __launch_bounds__(256) void prep_k(const float* __restrict__ E,
                                              unsigned short* __restrict__ Ebf,
                                              unsigned short* __restrict__ Etf,
                                              const float* __restrict__ T, float* __restrict__ Tt,
                                              const int* __restrict__ m_mask,
                                              int* __restrict__ rowidx, int* __restrict__ nactb,
                                              float* __restrict__ meansum) {
    __shared__ __align__(16) unsigned char psmem[8704];
    int blk = blockIdx.x;
    int t = threadIdx.x;
    if (blk < 1000) {
        unsigned short* tile = (unsigned short*)psmem;   // [32][136]
        int v0 = blk * 32;
#pragma unroll
        for (int i = 0; i < 4; ++i) {
            int idx = i * 256 + t;
            int v = idx >> 5;
            int d4 = (idx & 31) * 4;
            float4 val = *(const float4*)&E[(size_t)(v0 + v) * 128 + d4];
            tile[v * 136 + d4 + 0] = f2bf(val.x);
            tile[v * 136 + d4 + 1] = f2bf(val.y);
            tile[v * 136 + d4 + 2] = f2bf(val.z);
            tile[v * 136 + d4 + 3] = f2bf(val.w);
        }
        __syncthreads();
        {
            int fi = t >> 5;
            int l0 = (t & 31) * 2;
            int vtl = fi >> 2, s = fi & 3;
            size_t base = ((size_t)(blk * 2 + vtl) * 4 + s) * 512;
#pragma unroll
            for (int li = 0; li < 2; ++li) {
                int l = l0 + li;
                int nl = l & 15, hf = l >> 4;
                ushort8v o;
#pragma unroll
                for (int j = 0; j < 8; ++j) o[j] = tile[(vtl * 16 + nl) * 136 + s * 32 + hf * 8 + j];
                *(ushort8v*)&Ebf[base + l * 8] = o;
            }
        }
        {
            int ct = t >> 5;
            int l0 = (t & 31) * 2;
            size_t base = ((size_t)blk * 8 + ct) * 512;
#pragma unroll
            for (int li = 0; li < 2; ++li) {
                int l = l0 + li;
                int nl = l & 15, hf = l >> 4;
                ushort8v o;
#pragma unroll
                for (int j = 0; j < 8; ++j) o[j] = tile[(hf * 8 + j) * 136 + ct * 16 + nl];
                *(ushort8v*)&Etf[base + l * 8] = o;
            }
        }
    } else if (blk < 1256) {
        int tb = blk - 1000;
        for (int q = 0; q < 4; ++q) {
            int id = tb * 1024 + q * 256 + t;
            int k = id >> 17;
            int rem = id & 131071;
            int a = rem >> 10;
            int bc = rem & 1023;
            int b = bc >> 3, c = bc & 7;
            Tt[k * 131072 + b * 1024 + a * 8 + c] = T[id];
        }
    } else if (blk == 1256) {
        // compact with 256 threads over 512 rows
        int* wc = (int*)psmem;   // [8]
        bool a0 = m_mask[t] != 0;
        bool a1 = m_mask[t + 256] != 0;
        unsigned long long b0 = __ballot(a0);
        unsigned long long b1 = __ballot(a1);
        int w = t >> 6, lane = t & 63;
        if (lane == 0) { wc[w] = __popcll(b0); wc[4 + w] = __popcll(b1); }
        __syncthreads();
        int base0 = 0;
        for (int i = 0; i < w; ++i) base0 += wc[i];
        int base1 = 0;
        for (int i = 0; i < 4 + w; ++i) base1 += wc[i];
        if (a0) rowidx[base0 + __popcll(b0 & ((1ull << lane) - 1))] = t;
        if (a1) rowidx[base1 + __popcll(b1 & ((1ull << lane) - 1))] = t + 256;
        if (t == 0) {
            int tot = 0;
            for (int i = 0; i < 8; ++i) tot += wc[i];
            nactb[0] = tot;
        }
    } else {
        // colsum
        float* red = (float*)psmem;   // [256]
        int d = t & 127, h = t >> 7;
        int v0 = (blk - 1257) * 256;
        float s = 0.f;
        for (int p = 0; p < 128; ++p)
            s += E[(size_t)(v0 + h + 2 * p) * 128 + d];
        red[t] = s;
        __syncthreads();
        if (h == 0) atomicAdd(&meansum[d], red[d] + red[128 + d]);
    }
}

// ue = select(mm, colmean, x);  qz = softmax_D(ue*keep)*keep  (+ bf16 copy)
__global__ __launch_bounds__(64) void init_k(const float* __restrict__ x, const int* __restrict__ mask,
                                             const int* __restrict__ m_mask, const float* __restrict__ meansum,
                                             float* __restrict__ ue, float* __restrict__ qz,
                                             unsigned short* __restrict__ qzb) {
    int row = blockIdx.x, t = threadIdx.x;
    float keepv = mask[row] ? 1.f : 0.f;
    bool mm = m_mask[row] != 0;
    float pre0 = meansum[t] * (1.f / 32000.f);
    float pre1 = meansum[t + 64] * (1.f / 32000.f);
    float u0 = mm ? pre0 : x[row * 128 + t];
    float u1 = mm ? pre1 : x[row * 128 + t + 64];
    ue[row * 128 + t] = u0;
    ue[row * 128 + t + 64] = u1;
    float sv0 = u0 * keepv, sv1 = u1 * keepv;
    float m = fmaxf(sv0, sv1);
    for (int off = 32; off; off >>= 1) m = fmaxf(m, __shfl_xor(m, off));
    float e0 = __expf(sv0 - m), e1 = __expf(sv1 - m);
    float s = e0 + e1;
    for (int off = 32; off; off >>= 1) s += __shfl_xor(s, off);
    float inv = keepv / s;
    float q0 = e0 * inv, q1 = e1 * inv;
    qz[row * 128 + t] = q0;
    qz[row * 128 + t + 64] = q1;
    qzb[row * 128 + t] = f2bf(q0);
    qzb[row * 128 + t + 64] = f2bf(q1);
}

// ---------- per-iteration kernels ----------

// fusedA = uwgemm (blocks [0,512)) | pxe (blocks [512,2304)).  Independent parts.
__global__ __launch_bounds__(256) void fusedA_k(const float* __restrict__ qz, const float* __restrict__ T,
                                                const float* __restrict__ Tt, float* __restrict__ U2,
                                                unsigned short* __restrict__ Ut, unsigned short* __restrict__ Wt,
                                                const unsigned short* __restrict__ qzb,
                                                const unsigned short* __restrict__ Ebf,
                                                const unsigned short* __restrict__ Etf,
                                                const int* __restrict__ rowidx, const int* __restrict__ nactb,
                                                float* __restrict__ partial, float* __restrict__ partial_rs) {
    __shared__ __align__(16) unsigned char smem[42752];
    int blk = blockIdx.x;
    int t = threadIdx.x;
    if (blk < 512) {
        // ---- uwgemm ----
        float* aL = (float*)smem;           // [2048]
        int by = blk >> 5;                  // 16: uw(2) x z(4) x k(2)
        int uw = by >> 3, z = (by >> 1) & 3, k = by & 1;
        int bx = blk & 31;                  // 32: mt(8) x nt(4)
        int m0 = (bx >> 2) * 16, n = (bx & 3) * 256 + t;
        const float* A = qz + z * 16384;
        const float* Bm = (uw ? Tt : T) + k * 131072;
        for (int idx = t; idx < 2048; idx += 256)
            aL[idx] = A[(m0 + (idx >> 7)) * 128 + (idx & 127)];
        __syncthreads();
        float acc[16];
#pragma unroll
        for (int m = 0; m < 16; ++m) acc[m] = 0.f;
        for (int kq = 0; kq < 32; ++kq) {
            float b0 = Bm[(kq * 4 + 0) * 1024 + n];
            float b1 = Bm[(kq * 4 + 1) * 1024 + n];
            float b2 = Bm[(kq * 4 + 2) * 1024 + n];
            float b3 = Bm[(kq * 4 + 3) * 1024 + n];
#pragma unroll
            for (int m = 0; m < 16; ++m) {
                const float4 aq = *(const float4*)&aL[m * 128 + kq * 4];
                acc[m] += aq.x * b0 + aq.y * b1 + aq.z * b2 + aq.w * b3;
            }
        }
        if (uw == 0) {
            float* Cm = U2 + (z * 2 + k) * 131072;
#pragma unroll
            for (int m = 0; m < 16; ++m)
                Cm[(m0 + m) * 1024 + n] = acc[m];
        }
        int bb = n >> 3, cc = n & 7;
        ushort8v p0, p1;
#pragma unroll
        for (int m = 0; m < 8; ++m) { p0[m] = f2bf(acc[m]); p1[m] = f2bf(acc[8 + m]); }
        unsigned short* To = (uw ? Wt : Ut) + ((size_t)(z * 2 + k) * 128 + bb) * 1024 + cc * 128 + m0;
        *(ushort8v*)&To[0] = p0;
        *(ushort8v*)&To[8] = p1;
    } else {
        // ---- pxe (round-5 structure, NO atomics) ----
        int nact = nactb[0];
        int bid = blk - 512;                  // 0..1791
        int xcd = bid & 7, idx = bid >> 3;    // idx 0..223
        int g = xcd + 8 * (idx >> 5);         // v-group 0..55 (g>=50 dead)
        int bx = idx & 31;                    // row-tile
        int r0 = bx * 16;
        if (g >= 50 || r0 >= nact) return;
        unsigned short* Pl = (unsigned short*)smem;               // [4][2][576]
        float* slab = (float*)(smem + 9216);                      // [4][2080]
        float* rsW  = (float*)(smem + 9216 + 33280);              // [4][16]
        int w = t >> 6, lane = t & 63;
        int nloc = lane & 15, half = lane >> 4;
        int rA = r0 + nloc;
        bool actA = rA < nact;
        int rowA = actA ? rowidx[rA] : 0;
        short8 zero8 = (short8){0, 0, 0, 0, 0, 0, 0, 0};
        short8 afr[4];                         // qz frag (idx=z-row, k=d)
#pragma unroll
        for (int s = 0; s < 4; ++s) {
            short8 v = *(const short8*)&qzb[rowA * 128 + s * 32 + half * 8];
            afr[s] = actA ? v : zero8;
        }
        const int kc0 = g * 20 + w * 5;        // this wave's 5 chunks
        short8 ebb[2][8];                      // double-buffered Ebf frags
#pragma unroll
        for (int f = 0; f < 8; ++f)
            ebb[0][f] = *(const short8*)&Ebf[((size_t)(kc0 * 8 + f)) * 512 + lane * 8];
        f32x4 acc2[8];
#pragma unroll
        for (int ct = 0; ct < 8; ++ct) acc2[ct] = (f32x4){0.f, 0.f, 0.f, 0.f};
        float rsl = 0.f;
#pragma unroll
        for (int step = 0; step < 5; ++step) {
            const int p = step & 1;
            const int kc = kc0 + step;
            short8 et[8];                      // current Etf frags (issued early)
#pragma unroll
            for (int f = 0; f < 8; ++f)
                et[f] = *(const short8*)&Etf[((size_t)(kc * 8 + f)) * 512 + lane * 8];
            if (step < 4) {                    // prefetch next Ebf frags
#pragma unroll
                for (int f = 0; f < 8; ++f)
                    ebb[p ^ 1][f] = *(const short8*)&Ebf[((size_t)((kc + 1) * 8 + f)) * 512 + lane * 8];
            }
            // MFMA1 (swapped): D[v_local = half*4+reg][z = nloc], 2 chains
            f32x4 p0 = (f32x4){0.f, 0.f, 0.f, 0.f};
            f32x4 p1 = (f32x4){0.f, 0.f, 0.f, 0.f};
#pragma unroll
            for (int s = 0; s < 4; ++s) {
                p0 = __builtin_amdgcn_mfma_f32_16x16x32_bf16(ebb[p][s], afr[s], p0, 0, 0, 0);
                p1 = __builtin_amdgcn_mfma_f32_16x16x32_bf16(ebb[p][4 + s], afr[s], p1, 0, 0, 0);
            }
            unsigned short* pw = Pl + (w * 2 + p) * 576;
            {
                float e0 = __expf(p0[0]), e1 = __expf(p0[1]), e2 = __expf(p0[2]), e3 = __expf(p0[3]);
                rsl += (e0 + e1) + (e2 + e3);
                uint2 pk = {(unsigned)f2bf(e0) | ((unsigned)f2bf(e1) << 16),
                            (unsigned)f2bf(e2) | ((unsigned)f2bf(e3) << 16)};
                *(uint2*)&pw[nloc * 36 + half * 4] = pk;
            }
            {
                float e0 = __expf(p1[0]), e1 = __expf(p1[1]), e2 = __expf(p1[2]), e3 = __expf(p1[3]);
                rsl += (e0 + e1) + (e2 + e3);
                uint2 pk = {(unsigned)f2bf(e0) | ((unsigned)f2bf(e1) << 16),
                            (unsigned)f2bf(e2) | ((unsigned)f2bf(e3) << 16)};
                *(uint2*)&pw[nloc * 36 + 16 + half * 4] = pk;
            }
            short8 a2 = *(const short8*)&pw[nloc * 36 + half * 8];
#pragma unroll
            for (int ct = 0; ct < 8; ++ct)
                acc2[ct] = __builtin_amdgcn_mfma_f32_16x16x32_bf16(a2, et[ct], acc2[ct], 0, 0, 0);
        }
        rsl += __shfl_xor(rsl, 16);
        rsl += __shfl_xor(rsl, 32);
        if (lane < 16) rsW[w * 16 + nloc] = rsl;
#pragma unroll
        for (int ct = 0; ct < 8; ++ct)
#pragma unroll
            for (int reg = 0; reg < 4; ++reg)
                slab[w * 2080 + (half * 4 + reg) * 130 + ct * 16 + nloc] = acc2[ct][reg];
        __syncthreads();
        float* pb = partial + (size_t)g * 65536;
        for (int i = t; i < 2048; i += 256) {
            int row = i >> 7, col = i & 127;
            int rr = r0 + row;
            if (rr < nact)
                pb[rr * 128 + col] = slab[row * 130 + col] + slab[2080 + row * 130 + col]
                                   + slab[4160 + row * 130 + col] + slab[6240 + row * 130 + col];
        }
        if (t < 16) {
            int rr = r0 + t;
            if (rr < nact)
                partial_rs[g * 512 + rr] = rsW[t] + rsW[16 + t] + rsW[32 + t] + rsW[48 + t];
        }
    }
}

// fusedB = qhnF (blocks [0,256)) | reduce (blocks [256,512)); independent parts.
__global__ __launch_bounds__(256) void fusedB_k(const float* __restrict__ qz, const float* __restrict__ U2,
                                                const int* __restrict__ mask,
                                                unsigned short* __restrict__ A0b, unsigned short* __restrict__ A1b,
                                                unsigned short* __restrict__ A0Tb, unsigned short* __restrict__ A1Tb,
                                                const float* __restrict__ partial, const float* __restrict__ partial_rs,
                                                const int* __restrict__ rowidx, const int* __restrict__ nactb,
                                                float* __restrict__ exbuf, float* __restrict__ rowsum) {
    __shared__ __align__(16) unsigned char smem[23552];
    int blk = blockIdx.x;
    int t = threadIdx.x;
    if (blk >= 256) {
        // ---- reduce ----
        int nact = nactb[0];
        int idx = (blk - 256) * 256 + t;   // 0..65535
        int rr = idx >> 7, col = idx & 127;
        if (rr >= nact) return;
        float s = 0.f;
#pragma unroll 10
        for (int g = 0; g < 50; ++g)
            s += partial[(size_t)g * 65536 + rr * 128 + col];
        int row = rowidx[rr];
        exbuf[row * 128 + col] = s;
        if (col == 0) {
            float ts = 0.f;
#pragma unroll 10
            for (int g = 0; g < 50; ++g) ts += partial_rs[g * 512 + rr];
            rowsum[row] = ts;
        }
        return;
    }
    // ---- qhnF ----
    float* As = (float*)smem;                     // [2][16][36]
    float* Bs = (float*)(smem + 4608);            // [128][36]
    int* maskL = (int*)(smem + 4608 + 18432);     // [128]
    int z = blk >> 6, c = (blk >> 3) & 7, iq = blk & 7;
    int i0 = iq * 16;
    int tj = t & 15, ti = t >> 4;
    int i = i0 + ti;
    if (t < 128) maskL[t] = mask[z * 128 + t];
    float acc0[8], acc1[8];
#pragma unroll
    for (int jj = 0; jj < 8; ++jj) { acc0[jj] = 0.f; acc1[jj] = 0.f; }
    const float* U2z = U2 + (size_t)z * 262144;
    const float* qzz = qz + z * 16384;
    for (int kb = 0; kb < 4; ++kb) {
        int b0 = kb * 32;
        __syncthreads();
        for (int e = t; e < 1024; e += 256) {
            int k = e >> 9, r = e & 511, ii = r >> 5, b = r & 31;
            As[(k * 16 + ii) * 36 + b] = U2z[k * 131072 + (i0 + ii) * 1024 + (b0 + b) * 8 + c];
        }
        for (int f = t; f < 1024; f += 256) {
            int j = f >> 3, b4 = f & 7;
            int slot = b4 ^ ((j >> 3) & 7);
            *(float4*)&Bs[j * 36 + slot * 4] = *(const float4*)&qzz[j * 128 + b0 + b4 * 4];
        }
        __syncthreads();
#pragma unroll
        for (int b4 = 0; b4 < 8; ++b4) {
            float4 a0 = *(const float4*)&As[(0 * 16 + ti) * 36 + b4 * 4];
            float4 a1 = *(const float4*)&As[(1 * 16 + ti) * 36 + b4 * 4];
#pragma unroll
            for (int jj = 0; jj < 8; ++jj) {
                int j = tj * 8 + jj;
                int slot = b4 ^ ((j >> 3) & 7);
                float4 bq = *(const float4*)&Bs[j * 36 + slot * 4];
                acc0[jj] += a0.x * bq.x;
                acc0[jj] += a0.y * bq.y;
                acc0[jj] += a0.z * bq.z;
                acc0[jj] += a0.w * bq.w;
                acc1[jj] += a1.x * bq.x;
                acc1[jj] += a1.y * bq.y;
                acc1[jj] += a1.z * bq.z;
                acc1[jj] += a1.w * bq.w;
            }
        }
    }
    bool vi = maskL[i] != 0;
    float fv[8];
#pragma unroll
    for (int jj = 0; jj < 8; ++jj) {
        int j2 = tj * 8 + jj;
        float F = (j2 > i) ? acc0[jj] : acc1[jj];
        if (j2 == i) F -= NEGC;
        if (!vi || maskL[j2] == 0) F = -NEGC;
        fv[jj] = F;
    }
    float mval = fv[0];
#pragma unroll
    for (int jj = 1; jj < 8; ++jj) mval = fmaxf(mval, fv[jj]);
    for (int off = 1; off < 16; off <<= 1) mval = fmaxf(mval, __shfl_xor(mval, off));
    float ssum = 0.f;
#pragma unroll
    for (int jj = 0; jj < 8; ++jj) ssum += __expf(fv[jj] - mval);
    for (int off = 1; off < 16; off <<= 1) ssum += __shfl_xor(ssum, off);
    float inv = 1.f / ssum;
    size_t base = (size_t)(z * 8 + c) * 16384;
    ushort8v v0, v1;
    unsigned short bvv[8];
#pragma unroll
    for (int jj = 0; jj < 8; ++jj) {
        int j2 = tj * 8 + jj;
        float val = __expf(fv[jj] - mval) * inv;
        unsigned short bv = f2bf(val);
        bvv[jj] = bv;
        v0[jj] = (j2 > i) ? bv : (unsigned short)0;
        v1[jj] = (j2 < i) ? bv : (unsigned short)0;
    }
    *(ushort8v*)&A0b[base + i * 128 + tj * 8] = v0;
    *(ushort8v*)&A1b[base + i * 128 + tj * 8] = v1;
#pragma unroll
    for (int jj = 0; jj < 8; ++jj) {
        int j2 = tj * 8 + jj;
        A0Tb[base + j2 * 128 + i] = (i < j2) ? bvv[jj] : (unsigned short)0;
        A1Tb[base + j2 * 128 + i] = (i > j2) ? bvv[jj] : (unsigned short)0;
    }
}

// gkern as NT bf16 MFMA — 512 x 1-wave blocks (parallelism-preserving), with a
// "last-arriving block" zupd epilogue: each row-slab (z,itile) is covered by 16
// blocks (8 at x 2 modes); after storing G, each block fences + bumps a
// device-scope counter; the 16th performs zupd for the slab's 16 rows from
// global g1/g2 (identical math to the old zupd_k). Removes 4 dispatches.
__global__ __launch_bounds__(64) void gkern_mfma_k(const unsigned short* __restrict__ A0b,
                                                   const unsigned short* __restrict__ A1b,
                                                   const unsigned short* __restrict__ A0Tb,
                                                   const unsigned short* __restrict__ A1Tb,
                                                   const unsigned short* __restrict__ Ut,
                                                   const unsigned short* __restrict__ Wt,
                                                   float* __restrict__ g1, float* __restrict__ g2,
                                                   const float* __restrict__ ue, const float* __restrict__ x,
                                                   const int* __restrict__ m_mask,
                                                   const float* __restrict__ exbuf, const float* __restrict__ rowsum,
                                                   const int* __restrict__ mask,
                                                   float* __restrict__ qz, unsigned short* __restrict__ qzb,
                                                   unsigned int* __restrict__ ctr, int itArg, int useEx) {
    int mode = blockIdx.y;
    int bx = blockIdx.x;
    int z = bx >> 6, itile = (bx >> 3) & 7, at = bx & 7;
    int lane = threadIdx.x;
    int nloc = lane & 15, half = lane >> 4;
    int i0 = itile * 16, a0 = at * 16;
    const unsigned short* Am0 = (mode ? A0Tb : A0b) + (size_t)z * 131072;
    const unsigned short* Am1 = (mode ? A1Tb : A1b) + (size_t)z * 131072;
    const unsigned short* Bt = mode ? Ut : Wt;
    const unsigned short* B0 = Bt + (size_t)(z * 2 + 0) * 131072 + (size_t)(a0 + nloc) * 1024;
    const unsigned short* B1 = Bt + (size_t)(z * 2 + 1) * 131072 + (size_t)(a0 + nloc) * 1024;
    const unsigned short* Ar0 = Am0 + (size_t)(i0 + nloc) * 128;
    const unsigned short* Ar1 = Am1 + (size_t)(i0 + nloc) * 128;
    f32x4 acc = (f32x4){0.f, 0.f, 0.f, 0.f};
#pragma unroll
    for (int c = 0; c < 8; ++c) {
#pragma unroll
        for (int sb = 0; sb < 4; ++sb) {
            int s0 = sb * 32 + half * 8;
            short8 av0 = *(const short8*)&Ar0[c * 16384 + s0];
            short8 bv0 = *(const short8*)&B0[c * 128 + s0];
            acc = __builtin_amdgcn_mfma_f32_16x16x32_bf16(av0, bv0, acc, 0, 0, 0);
            short8 av1 = *(const short8*)&Ar1[c * 16384 + s0];
            short8 bv1 = *(const short8*)&B1[c * 128 + s0];
            acc = __builtin_amdgcn_mfma_f32_16x16x32_bf16(av1, bv1, acc, 0, 0, 0);
        }
    }
    float* G = mode ? g2 : g1;
#pragma unroll
    for (int reg = 0; reg < 4; ++reg)
        G[(z * 128 + i0 + half * 4 + reg) * 128 + a0 + nloc] = acc[reg];
    // ---- last-arriving-block zupd epilogue ----
    __threadfence();   // release G stores (device scope)
    int slab = z * 8 + itile;
    unsigned int old = 0;
    if (lane == 0) old = atomicAdd(&ctr[itArg * 32 + slab], 1u);
    old = __shfl(old, 0);
    if (old == 15u) {
        __threadfence();   // acquire other blocks' G stores
        for (int r = 0; r < 16; ++r) {
            int row = z * 128 + i0 + r;
            float keepv = mask[row] ? 1.f : 0.f;
            int b = row * 128;
            float u0, u1;
            if (useEx) {
                if (m_mask[row] != 0) {
                    float rsv = rowsum[row];
                    u0 = exbuf[b + lane] / rsv;
                    u1 = exbuf[b + lane + 64] / rsv;
                } else {
                    u0 = x[b + lane];
                    u1 = x[b + lane + 64];
                }
            } else {
                u0 = ue[b + lane];
                u1 = ue[b + lane + 64];
            }
            float v0 = u0 + g1[b + lane] + g2[b + lane];
            float v1 = u1 + g1[b + lane + 64] + g2[b + lane + 64];
            float m = fmaxf(v0, v1);
            for (int off = 32; off; off >>= 1) m = fmaxf(m, __shfl_xor(m, off));
            float e0 = __expf(v0 - m), e1 = __expf(v1 - m);
            float s = e0 + e1;
            for (int off = 32; off; off >>= 1) s += __shfl_xor(s, off);
            float inv = keepv / s;
            float q0 = e0 * inv, q1 = e1 * inv;
            qz[b + lane] = q0;
            qz[b + lane + 64] = q1;
            qzb[b + lane] = f2bf(q0);
            qzb[b + lane + 64] = f2bf(q1);
        }
    }
}

// out[row][v] = sum_a qz[row][a] * E[v][a]   — bf16 MFMA NT-GEMM (final only).
__global__ __launch_bounds__(256) void msgx_mfma_k(const unsigned short* __restrict__ qzb,
                                                   const unsigned short* __restrict__ Ebf,
                                                   float* __restrict__ out) {
    int t = threadIdx.x;
    int w = t >> 6, lane = t & 63;
    int nloc = lane & 15, half = lane >> 4;
    int rt0 = blockIdx.x * 64;
    int cb0 = blockIdx.y * 256 + w * 64;
    short8 afr[4][4];
#pragma unroll
    for (int r = 0; r < 4; ++r)
#pragma unroll
        for (int s = 0; s < 4; ++s)
            afr[r][s] = *(const short8*)&qzb[(rt0 + r * 16 + nloc) * 128 + s * 32 + half * 8];
    f32x4 acc[4][4];
#pragma unroll
    for (int r = 0; r < 4; ++r)
#pragma unroll
        for (int ct = 0; ct < 4; ++ct)
            acc[r][ct] = (f32x4){0.f, 0.f, 0.f, 0.f};
#pragma unroll
    for (int ct = 0; ct < 4; ++ct) {
#pragma unroll
        for (int s = 0; s < 4; ++s) {
            short8 bfr = *(const short8*)&Ebf[(((size_t)(cb0 >> 4) + ct) * 4 + s) * 512 + lane * 8];
#pragma unroll
            for (int r = 0; r < 4; ++r)
                acc[r][ct] = __builtin_amdgcn_mfma_f32_16x16x32_bf16(afr[r][s], bfr, acc[r][ct], 0, 0, 0);
        }
    }
#pragma unroll
    for (int r = 0; r < 4; ++r)
#pragma unroll
        for (int ct = 0; ct < 4; ++ct) {
            int col = cb0 + ct * 16 + nloc;
#pragma unroll
            for (int reg = 0; reg < 4; ++reg) {
                int row = rt0 + r * 16 + half * 4 + reg;
                out[(size_t)row * V_ + col] = acc[r][ct][reg];
            }
        }
}

extern "C" void kernel_launch(void* const* d_in, const int* in_sizes, int n_in,
                              void* d_out, int out_size, void* d_ws, size_t ws_size,
                              hipStream_t stream) {
    const float* x     = (const float*)d_in[0];   // [B,L,D]
    const int*   mask  = (const int*)d_in[1];     // [B,L]
    const float* E     = (const float*)d_in[2];   // [V,D]
    const int*   mmask = (const int*)d_in[3];     // [B,L]
    const float* T     = (const float*)d_in[4];   // [2,D,D,H]
    float* out = (float*)d_out;                   // [B,L,V]

    float* w = (float*)d_ws;
    float* meansum = w;                           // 128 floats
    unsigned int* ctr = (unsigned int*)(w + 128); // 128 u32 (zupd-epilogue counters)
    float* ue      = w + 256;           // 65536
    float* qz      = ue + 65536;        // 65536
    float* exbuf   = qz + 65536;        // 65536
    float* rowsum  = exbuf + 65536;     // 512
    float* g1      = rowsum + 512;      // 65536
    float* g2      = g1 + 65536;        // 65536
    float* Tt      = g2 + 65536;        // 262144
    float* U2      = Tt + 262144;       // 1048576 (fp32, qhnF input)
    float* prs     = U2 + 1048576;      // 25600 (partial row-sums [50][512])
    unsigned short* qzb  = (unsigned short*)(prs + 25600);   // 65536
    unsigned short* Ebf  = qzb + 65536;                      // 4,096,000
    unsigned short* Etf  = Ebf + 4096000;                    // 4,096,000
    unsigned short* A0b  = Etf + 4096000;                    // 524288
    unsigned short* A1b  = A0b + 524288;                     // 524288
    unsigned short* A0Tb = A1b + 524288;                     // 524288
    unsigned short* A1Tb = A0Tb + 524288;                    // 524288
    unsigned short* Ut   = A1Tb + 524288;                    // 1048576
    unsigned short* Wt   = Ut + 1048576;                     // 1048576
    int* rowidx = (int*)(Wt + 1048576);                      // 512
    int* nactb  = rowidx + 512;                              // 16

    // partial exbuf slabs [50][512][128] f32 = 13.1 MB, live only between
    // fusedA and fusedB -> reuse d_out (65.5 MB, dead until final msgx).
    float* partial = out;

    // one memset covers meansum (128 f32) + ctr (128 u32)
    hipMemsetAsync(w, 0, 256 * sizeof(float), stream);
    prep_k<<<1382, 256, 0, stream>>>(E, Ebf, Etf, T, Tt, mmask, rowidx, nactb, meansum);
    init_k<<<512, 64, 0, stream>>>(x, mask, mmask, meansum, ue, qz, qzb);

    for (int it = 0; it < 4; ++it) {
        fusedA_k<<<it ? 2304 : 512, 256, 0, stream>>>(qz, T, Tt, U2, Ut, Wt,
                                                      qzb, Ebf, Etf, rowidx, nactb, partial, prs);
        fusedB_k<<<it ? 512 : 256, 256, 0, stream>>>(qz, U2, mask, A0b, A1b, A0Tb, A1Tb,
                                                     partial, prs, rowidx, nactb, exbuf, rowsum);
        gkern_mfma_k<<<dim3(256, 2), 64, 0, stream>>>(A0b, A1b, A0Tb, A1Tb, Ut, Wt, g1, g2,
                                                      ue, x, mmask, exbuf, rowsum, mask, qz, qzb,
                                                      ctr, it, it ? 1 : 0);
    }
    msgx_mfma_k<<<dim3(8, 125), 256, 0, stream>>>(qzb, Ebf, out);
}

// Round 13
// 377.995 us; speedup vs baseline: 3.7133x; 1.2551x over previous
//
#include <hip/hip_runtime.h>
#include <math.h>

#define L_ 128
#define D_ 128
#define H_ 8
#define V_ 32000
#define NEGC 1e9f

typedef short short8 __attribute__((ext_vector_type(8)));
typedef float f32x4 __attribute__((ext_vector_type(4)));
typedef unsigned short ushort8v __attribute__((ext_vector_type(8)));

__device__ __forceinline__ unsigned short f2bf(float x) {
    unsigned int u = __float_as_uint(x);
    unsigned int r = (u + 0x7fff + ((u >> 16) & 1)) >> 16;
    return (unsigned short)r;
}

// ---------- one-time precompute ----------

// prep_k = frag (blocks [0,1000)) | transT ([1000,1256)) | compact (1256)
//        | colsum ([1257,1382)) — all 256 thr, independent parts.
__global__ __launch_bounds__(256) void prep_k(const float* __restrict__ E,
                                              unsigned short* __restrict__ Ebf,
                                              unsigned short* __restrict__ Etf,
                                              const float* __restrict__ T, float* __restrict__ Tt,
                                              const int* __restrict__ m_mask,
                                              int* __restrict__ rowidx, int* __restrict__ nactb,
                                              float* __restrict__ meansum) {
    __shared__ __align__(16) unsigned char psmem[8704];
    int blk = blockIdx.x;
    int t = threadIdx.x;
    if (blk < 1000) {
        unsigned short* tile = (unsigned short*)psmem;   // [32][136]
        int v0 = blk * 32;
#pragma unroll
        for (int i = 0; i < 4; ++i) {
            int idx = i * 256 + t;
            int v = idx >> 5;
            int d4 = (idx & 31) * 4;
            float4 val = *(const float4*)&E[(size_t)(v0 + v) * 128 + d4];
            tile[v * 136 + d4 + 0] = f2bf(val.x);
            tile[v * 136 + d4 + 1] = f2bf(val.y);
            tile[v * 136 + d4 + 2] = f2bf(val.z);
            tile[v * 136 + d4 + 3] = f2bf(val.w);
        }
        __syncthreads();
        {
            int fi = t >> 5;
            int l0 = (t & 31) * 2;
            int vtl = fi >> 2, s = fi & 3;
            size_t base = ((size_t)(blk * 2 + vtl) * 4 + s) * 512;
#pragma unroll
            for (int li = 0; li < 2; ++li) {
                int l = l0 + li;
                int nl = l & 15, hf = l >> 4;
                ushort8v o;
#pragma unroll
                for (int j = 0; j < 8; ++j) o[j] = tile[(vtl * 16 + nl) * 136 + s * 32 + hf * 8 + j];
                *(ushort8v*)&Ebf[base + l * 8] = o;
            }
        }
        {
            int ct = t >> 5;
            int l0 = (t & 31) * 2;
            size_t base = ((size_t)blk * 8 + ct) * 512;
#pragma unroll
            for (int li = 0; li < 2; ++li) {
                int l = l0 + li;
                int nl = l & 15, hf = l >> 4;
                ushort8v o;
#pragma unroll
                for (int j = 0; j < 8; ++j) o[j] = tile[(hf * 8 + j) * 136 + ct * 16 + nl];
                *(ushort8v*)&Etf[base + l * 8] = o;
            }
        }
    } else if (blk < 1256) {
        int tb = blk - 1000;
        for (int q = 0; q < 4; ++q) {
            int id = tb * 1024 + q * 256 + t;
            int k = id >> 17;
            int rem = id & 131071;
            int a = rem >> 10;
            int bc = rem & 1023;
            int b = bc >> 3, c = bc & 7;
            Tt[k * 131072 + b * 1024 + a * 8 + c] = T[id];
        }
    } else if (blk == 1256) {
        // compact with 256 threads over 512 rows
        int* wc = (int*)psmem;   // [8]
        bool a0 = m_mask[t] != 0;
        bool a1 = m_mask[t + 256] != 0;
        unsigned long long b0 = __ballot(a0);
        unsigned long long b1 = __ballot(a1);
        int w = t >> 6, lane = t & 63;
        if (lane == 0) { wc[w] = __popcll(b0); wc[4 + w] = __popcll(b1); }
        __syncthreads();
        int base0 = 0;
        for (int i = 0; i < w; ++i) base0 += wc[i];
        int base1 = 0;
        for (int i = 0; i < 4 + w; ++i) base1 += wc[i];
        if (a0) rowidx[base0 + __popcll(b0 & ((1ull << lane) - 1))] = t;
        if (a1) rowidx[base1 + __popcll(b1 & ((1ull << lane) - 1))] = t + 256;
        if (t == 0) {
            int tot = 0;
            for (int i = 0; i < 8; ++i) tot += wc[i];
            nactb[0] = tot;
        }
    } else {
        // colsum
        float* red = (float*)psmem;   // [256]
        int d = t & 127, h = t >> 7;
        int v0 = (blk - 1257) * 256;
        float s = 0.f;
        for (int p = 0; p < 128; ++p)
            s += E[(size_t)(v0 + h + 2 * p) * 128 + d];
        red[t] = s;
        __syncthreads();
        if (h == 0) atomicAdd(&meansum[d], red[d] + red[128 + d]);
    }
}

// ue = select(mm, colmean, x);  qz = softmax_D(ue*keep)*keep  (+ bf16 copy)
__global__ __launch_bounds__(64) void init_k(const float* __restrict__ x, const int* __restrict__ mask,
                                             const int* __restrict__ m_mask, const float* __restrict__ meansum,
                                             float* __restrict__ ue, float* __restrict__ qz,
                                             unsigned short* __restrict__ qzb) {
    int row = blockIdx.x, t = threadIdx.x;
    float keepv = mask[row] ? 1.f : 0.f;
    bool mm = m_mask[row] != 0;
    float pre0 = meansum[t] * (1.f / 32000.f);
    float pre1 = meansum[t + 64] * (1.f / 32000.f);
    float u0 = mm ? pre0 : x[row * 128 + t];
    float u1 = mm ? pre1 : x[row * 128 + t + 64];
    ue[row * 128 + t] = u0;
    ue[row * 128 + t + 64] = u1;
    float sv0 = u0 * keepv, sv1 = u1 * keepv;
    float m = fmaxf(sv0, sv1);
    for (int off = 32; off; off >>= 1) m = fmaxf(m, __shfl_xor(m, off));
    float e0 = __expf(sv0 - m), e1 = __expf(sv1 - m);
    float s = e0 + e1;
    for (int off = 32; off; off >>= 1) s += __shfl_xor(s, off);
    float inv = keepv / s;
    float q0 = e0 * inv, q1 = e1 * inv;
    qz[row * 128 + t] = q0;
    qz[row * 128 + t + 64] = q1;
    qzb[row * 128 + t] = f2bf(q0);
    qzb[row * 128 + t + 64] = f2bf(q1);
}

// ---------- per-iteration kernels ----------

// fusedA = uwgemm (blocks [0,512)) | pxe (blocks [512,2304)).  Independent parts.
__global__ __launch_bounds__(256) void fusedA_k(const float* __restrict__ qz, const float* __restrict__ T,
                                                const float* __restrict__ Tt, float* __restrict__ U2,
                                                unsigned short* __restrict__ Ut, unsigned short* __restrict__ Wt,
                                                const unsigned short* __restrict__ qzb,
                                                const unsigned short* __restrict__ Ebf,
                                                const unsigned short* __restrict__ Etf,
                                                const int* __restrict__ rowidx, const int* __restrict__ nactb,
                                                float* __restrict__ partial, float* __restrict__ partial_rs) {
    __shared__ __align__(16) unsigned char smem[42752];
    int blk = blockIdx.x;
    int t = threadIdx.x;
    if (blk < 512) {
        // ---- uwgemm ----
        float* aL = (float*)smem;           // [2048]
        int by = blk >> 5;                  // 16: uw(2) x z(4) x k(2)
        int uw = by >> 3, z = (by >> 1) & 3, k = by & 1;
        int bx = blk & 31;                  // 32: mt(8) x nt(4)
        int m0 = (bx >> 2) * 16, n = (bx & 3) * 256 + t;
        const float* A = qz + z * 16384;
        const float* Bm = (uw ? Tt : T) + k * 131072;
        for (int idx = t; idx < 2048; idx += 256)
            aL[idx] = A[(m0 + (idx >> 7)) * 128 + (idx & 127)];
        __syncthreads();
        float acc[16];
#pragma unroll
        for (int m = 0; m < 16; ++m) acc[m] = 0.f;
        for (int kq = 0; kq < 32; ++kq) {
            float b0 = Bm[(kq * 4 + 0) * 1024 + n];
            float b1 = Bm[(kq * 4 + 1) * 1024 + n];
            float b2 = Bm[(kq * 4 + 2) * 1024 + n];
            float b3 = Bm[(kq * 4 + 3) * 1024 + n];
#pragma unroll
            for (int m = 0; m < 16; ++m) {
                const float4 aq = *(const float4*)&aL[m * 128 + kq * 4];
                acc[m] += aq.x * b0 + aq.y * b1 + aq.z * b2 + aq.w * b3;
            }
        }
        if (uw == 0) {
            float* Cm = U2 + (z * 2 + k) * 131072;
#pragma unroll
            for (int m = 0; m < 16; ++m)
                Cm[(m0 + m) * 1024 + n] = acc[m];
        }
        int bb = n >> 3, cc = n & 7;
        ushort8v p0, p1;
#pragma unroll
        for (int m = 0; m < 8; ++m) { p0[m] = f2bf(acc[m]); p1[m] = f2bf(acc[8 + m]); }
        unsigned short* To = (uw ? Wt : Ut) + ((size_t)(z * 2 + k) * 128 + bb) * 1024 + cc * 128 + m0;
        *(ushort8v*)&To[0] = p0;
        *(ushort8v*)&To[8] = p1;
    } else {
        // ---- pxe (round-5 structure, NO atomics) ----
        int nact = nactb[0];
        int bid = blk - 512;                  // 0..1791
        int xcd = bid & 7, idx = bid >> 3;    // idx 0..223
        int g = xcd + 8 * (idx >> 5);         // v-group 0..55 (g>=50 dead)
        int bx = idx & 31;                    // row-tile
        int r0 = bx * 16;
        if (g >= 50 || r0 >= nact) return;
        unsigned short* Pl = (unsigned short*)smem;               // [4][2][576]
        float* slab = (float*)(smem + 9216);                      // [4][2080]
        float* rsW  = (float*)(smem + 9216 + 33280);              // [4][16]
        int w = t >> 6, lane = t & 63;
        int nloc = lane & 15, half = lane >> 4;
        int rA = r0 + nloc;
        bool actA = rA < nact;
        int rowA = actA ? rowidx[rA] : 0;
        short8 zero8 = (short8){0, 0, 0, 0, 0, 0, 0, 0};
        short8 afr[4];                         // qz frag (idx=z-row, k=d)
#pragma unroll
        for (int s = 0; s < 4; ++s) {
            short8 v = *(const short8*)&qzb[rowA * 128 + s * 32 + half * 8];
            afr[s] = actA ? v : zero8;
        }
        const int kc0 = g * 20 + w * 5;        // this wave's 5 chunks
        short8 ebb[2][8];                      // double-buffered Ebf frags
#pragma unroll
        for (int f = 0; f < 8; ++f)
            ebb[0][f] = *(const short8*)&Ebf[((size_t)(kc0 * 8 + f)) * 512 + lane * 8];
        f32x4 acc2[8];
#pragma unroll
        for (int ct = 0; ct < 8; ++ct) acc2[ct] = (f32x4){0.f, 0.f, 0.f, 0.f};
        float rsl = 0.f;
#pragma unroll
        for (int step = 0; step < 5; ++step) {
            const int p = step & 1;
            const int kc = kc0 + step;
            short8 et[8];                      // current Etf frags (issued early)
#pragma unroll
            for (int f = 0; f < 8; ++f)
                et[f] = *(const short8*)&Etf[((size_t)(kc * 8 + f)) * 512 + lane * 8];
            if (step < 4) {                    // prefetch next Ebf frags
#pragma unroll
                for (int f = 0; f < 8; ++f)
                    ebb[p ^ 1][f] = *(const short8*)&Ebf[((size_t)((kc + 1) * 8 + f)) * 512 + lane * 8];
            }
            // MFMA1 (swapped): D[v_local = half*4+reg][z = nloc], 2 chains
            f32x4 p0 = (f32x4){0.f, 0.f, 0.f, 0.f};
            f32x4 p1 = (f32x4){0.f, 0.f, 0.f, 0.f};
#pragma unroll
            for (int s = 0; s < 4; ++s) {
                p0 = __builtin_amdgcn_mfma_f32_16x16x32_bf16(ebb[p][s], afr[s], p0, 0, 0, 0);
                p1 = __builtin_amdgcn_mfma_f32_16x16x32_bf16(ebb[p][4 + s], afr[s], p1, 0, 0, 0);
            }
            unsigned short* pw = Pl + (w * 2 + p) * 576;
            {
                float e0 = __expf(p0[0]), e1 = __expf(p0[1]), e2 = __expf(p0[2]), e3 = __expf(p0[3]);
                rsl += (e0 + e1) + (e2 + e3);
                uint2 pk = {(unsigned)f2bf(e0) | ((unsigned)f2bf(e1) << 16),
                            (unsigned)f2bf(e2) | ((unsigned)f2bf(e3) << 16)};
                *(uint2*)&pw[nloc * 36 + half * 4] = pk;
            }
            {
                float e0 = __expf(p1[0]), e1 = __expf(p1[1]), e2 = __expf(p1[2]), e3 = __expf(p1[3]);
                rsl += (e0 + e1) + (e2 + e3);
                uint2 pk = {(unsigned)f2bf(e0) | ((unsigned)f2bf(e1) << 16),
                            (unsigned)f2bf(e2) | ((unsigned)f2bf(e3) << 16)};
                *(uint2*)&pw[nloc * 36 + 16 + half * 4] = pk;
            }
            short8 a2 = *(const short8*)&pw[nloc * 36 + half * 8];
#pragma unroll
            for (int ct = 0; ct < 8; ++ct)
                acc2[ct] = __builtin_amdgcn_mfma_f32_16x16x32_bf16(a2, et[ct], acc2[ct], 0, 0, 0);
        }
        rsl += __shfl_xor(rsl, 16);
        rsl += __shfl_xor(rsl, 32);
        if (lane < 16) rsW[w * 16 + nloc] = rsl;
#pragma unroll
        for (int ct = 0; ct < 8; ++ct)
#pragma unroll
            for (int reg = 0; reg < 4; ++reg)
                slab[w * 2080 + (half * 4 + reg) * 130 + ct * 16 + nloc] = acc2[ct][reg];
        __syncthreads();
        float* pb = partial + (size_t)g * 65536;
        for (int i = t; i < 2048; i += 256) {
            int row = i >> 7, col = i & 127;
            int rr = r0 + row;
            if (rr < nact)
                pb[rr * 128 + col] = slab[row * 130 + col] + slab[2080 + row * 130 + col]
                                   + slab[4160 + row * 130 + col] + slab[6240 + row * 130 + col];
        }
        if (t < 16) {
            int rr = r0 + t;
            if (rr < nact)
                partial_rs[g * 512 + rr] = rsW[t] + rsW[16 + t] + rsW[32 + t] + rsW[48 + t];
        }
    }
}

// fusedB = qhnF (blocks [0,256)) | reduce (blocks [256,512)); independent parts.
__global__ __launch_bounds__(256) void fusedB_k(const float* __restrict__ qz, const float* __restrict__ U2,
                                                const int* __restrict__ mask,
                                                unsigned short* __restrict__ A0b, unsigned short* __restrict__ A1b,
                                                unsigned short* __restrict__ A0Tb, unsigned short* __restrict__ A1Tb,
                                                const float* __restrict__ partial, const float* __restrict__ partial_rs,
                                                const int* __restrict__ rowidx, const int* __restrict__ nactb,
                                                float* __restrict__ exbuf, float* __restrict__ rowsum) {
    __shared__ __align__(16) unsigned char smem[23552];
    int blk = blockIdx.x;
    int t = threadIdx.x;
    if (blk >= 256) {
        // ---- reduce ----
        int nact = nactb[0];
        int idx = (blk - 256) * 256 + t;   // 0..65535
        int rr = idx >> 7, col = idx & 127;
        if (rr >= nact) return;
        float s = 0.f;
#pragma unroll 10
        for (int g = 0; g < 50; ++g)
            s += partial[(size_t)g * 65536 + rr * 128 + col];
        int row = rowidx[rr];
        exbuf[row * 128 + col] = s;
        if (col == 0) {
            float ts = 0.f;
#pragma unroll 10
            for (int g = 0; g < 50; ++g) ts += partial_rs[g * 512 + rr];
            rowsum[row] = ts;
        }
        return;
    }
    // ---- qhnF ----
    float* As = (float*)smem;                     // [2][16][36]
    float* Bs = (float*)(smem + 4608);            // [128][36]
    int* maskL = (int*)(smem + 4608 + 18432);     // [128]
    int z = blk >> 6, c = (blk >> 3) & 7, iq = blk & 7;
    int i0 = iq * 16;
    int tj = t & 15, ti = t >> 4;
    int i = i0 + ti;
    if (t < 128) maskL[t] = mask[z * 128 + t];
    float acc0[8], acc1[8];
#pragma unroll
    for (int jj = 0; jj < 8; ++jj) { acc0[jj] = 0.f; acc1[jj] = 0.f; }
    const float* U2z = U2 + (size_t)z * 262144;
    const float* qzz = qz + z * 16384;
    for (int kb = 0; kb < 4; ++kb) {
        int b0 = kb * 32;
        __syncthreads();
        for (int e = t; e < 1024; e += 256) {
            int k = e >> 9, r = e & 511, ii = r >> 5, b = r & 31;
            As[(k * 16 + ii) * 36 + b] = U2z[k * 131072 + (i0 + ii) * 1024 + (b0 + b) * 8 + c];
        }
        for (int f = t; f < 1024; f += 256) {
            int j = f >> 3, b4 = f & 7;
            int slot = b4 ^ ((j >> 3) & 7);
            *(float4*)&Bs[j * 36 + slot * 4] = *(const float4*)&qzz[j * 128 + b0 + b4 * 4];
        }
        __syncthreads();
#pragma unroll
        for (int b4 = 0; b4 < 8; ++b4) {
            float4 a0 = *(const float4*)&As[(0 * 16 + ti) * 36 + b4 * 4];
            float4 a1 = *(const float4*)&As[(1 * 16 + ti) * 36 + b4 * 4];
#pragma unroll
            for (int jj = 0; jj < 8; ++jj) {
                int j = tj * 8 + jj;
                int slot = b4 ^ ((j >> 3) & 7);
                float4 bq = *(const float4*)&Bs[j * 36 + slot * 4];
                acc0[jj] += a0.x * bq.x;
                acc0[jj] += a0.y * bq.y;
                acc0[jj] += a0.z * bq.z;
                acc0[jj] += a0.w * bq.w;
                acc1[jj] += a1.x * bq.x;
                acc1[jj] += a1.y * bq.y;
                acc1[jj] += a1.z * bq.z;
                acc1[jj] += a1.w * bq.w;
            }
        }
    }
    bool vi = maskL[i] != 0;
    float fv[8];
#pragma unroll
    for (int jj = 0; jj < 8; ++jj) {
        int j2 = tj * 8 + jj;
        float F = (j2 > i) ? acc0[jj] : acc1[jj];
        if (j2 == i) F -= NEGC;
        if (!vi || maskL[j2] == 0) F = -NEGC;
        fv[jj] = F;
    }
    float mval = fv[0];
#pragma unroll
    for (int jj = 1; jj < 8; ++jj) mval = fmaxf(mval, fv[jj]);
    for (int off = 1; off < 16; off <<= 1) mval = fmaxf(mval, __shfl_xor(mval, off));
    float ssum = 0.f;
#pragma unroll
    for (int jj = 0; jj < 8; ++jj) ssum += __expf(fv[jj] - mval);
    for (int off = 1; off < 16; off <<= 1) ssum += __shfl_xor(ssum, off);
    float inv = 1.f / ssum;
    size_t base = (size_t)(z * 8 + c) * 16384;
    ushort8v v0, v1;
    unsigned short bvv[8];
#pragma unroll
    for (int jj = 0; jj < 8; ++jj) {
        int j2 = tj * 8 + jj;
        float val = __expf(fv[jj] - mval) * inv;
        unsigned short bv = f2bf(val);
        bvv[jj] = bv;
        v0[jj] = (j2 > i) ? bv : (unsigned short)0;
        v1[jj] = (j2 < i) ? bv : (unsigned short)0;
    }
    *(ushort8v*)&A0b[base + i * 128 + tj * 8] = v0;
    *(ushort8v*)&A1b[base + i * 128 + tj * 8] = v1;
#pragma unroll
    for (int jj = 0; jj < 8; ++jj) {
        int j2 = tj * 8 + jj;
        A0Tb[base + j2 * 128 + i] = (i < j2) ? bvv[jj] : (unsigned short)0;
        A1Tb[base + j2 * 128 + i] = (i > j2) ? bvv[jj] : (unsigned short)0;
    }
}

// gkern as NT bf16 MFMA — 512 x 1-wave blocks (parallelism-preserving form).
__global__ __launch_bounds__(64) void gkern_mfma_k(const unsigned short* __restrict__ A0b,
                                                   const unsigned short* __restrict__ A1b,
                                                   const unsigned short* __restrict__ A0Tb,
                                                   const unsigned short* __restrict__ A1Tb,
                                                   const unsigned short* __restrict__ Ut,
                                                   const unsigned short* __restrict__ Wt,
                                                   float* __restrict__ g1, float* __restrict__ g2) {
    int mode = blockIdx.y;
    int bx = blockIdx.x;
    int z = bx >> 6, it = (bx >> 3) & 7, at = bx & 7;
    int lane = threadIdx.x;
    int nloc = lane & 15, half = lane >> 4;
    int i0 = it * 16, a0 = at * 16;
    const unsigned short* Am0 = (mode ? A0Tb : A0b) + (size_t)z * 131072;
    const unsigned short* Am1 = (mode ? A1Tb : A1b) + (size_t)z * 131072;
    const unsigned short* Bt = mode ? Ut : Wt;
    const unsigned short* B0 = Bt + (size_t)(z * 2 + 0) * 131072 + (size_t)(a0 + nloc) * 1024;
    const unsigned short* B1 = Bt + (size_t)(z * 2 + 1) * 131072 + (size_t)(a0 + nloc) * 1024;
    const unsigned short* Ar0 = Am0 + (size_t)(i0 + nloc) * 128;
    const unsigned short* Ar1 = Am1 + (size_t)(i0 + nloc) * 128;
    f32x4 acc = (f32x4){0.f, 0.f, 0.f, 0.f};
#pragma unroll
    for (int c = 0; c < 8; ++c) {
#pragma unroll
        for (int sb = 0; sb < 4; ++sb) {
            int s0 = sb * 32 + half * 8;
            short8 av0 = *(const short8*)&Ar0[c * 16384 + s0];
            short8 bv0 = *(const short8*)&B0[c * 128 + s0];
            acc = __builtin_amdgcn_mfma_f32_16x16x32_bf16(av0, bv0, acc, 0, 0, 0);
            short8 av1 = *(const short8*)&Ar1[c * 16384 + s0];
            short8 bv1 = *(const short8*)&B1[c * 128 + s0];
            acc = __builtin_amdgcn_mfma_f32_16x16x32_bf16(av1, bv1, acc, 0, 0, 0);
        }
    }
    float* G = mode ? g2 : g1;
#pragma unroll
    for (int reg = 0; reg < 4; ++reg)
        G[(z * 128 + i0 + half * 4 + reg) * 128 + a0 + nloc] = acc[reg];
}

// qz = softmax_D(u + g1 + g2) * keep  (+ bf16 copy)
__global__ __launch_bounds__(64) void zupd_k(const float* __restrict__ ue, const float* __restrict__ x,
                                             const int* __restrict__ m_mask,
                                             const float* __restrict__ exbuf, const float* __restrict__ rowsum,
                                             const float* __restrict__ g1, const float* __restrict__ g2,
                                             const int* __restrict__ mask,
                                             float* __restrict__ qz, unsigned short* __restrict__ qzb, int useEx) {
    int row = blockIdx.x, t = threadIdx.x;
    float keepv = mask[row] ? 1.f : 0.f;
    int b = row * 128;
    float u0, u1;
    if (useEx) {
        if (m_mask[row] != 0) {
            float rsv = rowsum[row];
            u0 = exbuf[b + t] / rsv;
            u1 = exbuf[b + t + 64] / rsv;
        } else {
            u0 = x[b + t];
            u1 = x[b + t + 64];
        }
    } else {
        u0 = ue[b + t];
        u1 = ue[b + t + 64];
    }
    float v0 = u0 + g1[b + t] + g2[b + t];
    float v1 = u1 + g1[b + t + 64] + g2[b + t + 64];
    float m = fmaxf(v0, v1);
    for (int off = 32; off; off >>= 1) m = fmaxf(m, __shfl_xor(m, off));
    float e0 = __expf(v0 - m), e1 = __expf(v1 - m);
    float s = e0 + e1;
    for (int off = 32; off; off >>= 1) s += __shfl_xor(s, off);
    float inv = keepv / s;
    float q0 = e0 * inv, q1 = e1 * inv;
    qz[b + t] = q0;
    qz[b + t + 64] = q1;
    qzb[b + t] = f2bf(q0);
    qzb[b + t + 64] = f2bf(q1);
}

// out[row][v] = sum_a qz[row][a] * E[v][a]   — bf16 MFMA NT-GEMM (final only).
__global__ __launch_bounds__(256) void msgx_mfma_k(const unsigned short* __restrict__ qzb,
                                                   const unsigned short* __restrict__ Ebf,
                                                   float* __restrict__ out) {
    int t = threadIdx.x;
    int w = t >> 6, lane = t & 63;
    int nloc = lane & 15, half = lane >> 4;
    int rt0 = blockIdx.x * 64;
    int cb0 = blockIdx.y * 256 + w * 64;
    short8 afr[4][4];
#pragma unroll
    for (int r = 0; r < 4; ++r)
#pragma unroll
        for (int s = 0; s < 4; ++s)
            afr[r][s] = *(const short8*)&qzb[(rt0 + r * 16 + nloc) * 128 + s * 32 + half * 8];
    f32x4 acc[4][4];
#pragma unroll
    for (int r = 0; r < 4; ++r)
#pragma unroll
        for (int ct = 0; ct < 4; ++ct)
            acc[r][ct] = (f32x4){0.f, 0.f, 0.f, 0.f};
#pragma unroll
    for (int ct = 0; ct < 4; ++ct) {
#pragma unroll
        for (int s = 0; s < 4; ++s) {
            short8 bfr = *(const short8*)&Ebf[(((size_t)(cb0 >> 4) + ct) * 4 + s) * 512 + lane * 8];
#pragma unroll
            for (int r = 0; r < 4; ++r)
                acc[r][ct] = __builtin_amdgcn_mfma_f32_16x16x32_bf16(afr[r][s], bfr, acc[r][ct], 0, 0, 0);
        }
    }
#pragma unroll
    for (int r = 0; r < 4; ++r)
#pragma unroll
        for (int ct = 0; ct < 4; ++ct) {
            int col = cb0 + ct * 16 + nloc;
#pragma unroll
            for (int reg = 0; reg < 4; ++reg) {
                int row = rt0 + r * 16 + half * 4 + reg;
                out[(size_t)row * V_ + col] = acc[r][ct][reg];
            }
        }
}

extern "C" void kernel_launch(void* const* d_in, const int* in_sizes, int n_in,
                              void* d_out, int out_size, void* d_ws, size_t ws_size,
                              hipStream_t stream) {
    const float* x     = (const float*)d_in[0];   // [B,L,D]
    const int*   mask  = (const int*)d_in[1];     // [B,L]
    const float* E     = (const float*)d_in[2];   // [V,D]
    const int*   mmask = (const int*)d_in[3];     // [B,L]
    const float* T     = (const float*)d_in[4];   // [2,D,D,H]
    float* out = (float*)d_out;                   // [B,L,V]

    float* w = (float*)d_ws;
    float* meansum = w;                 // 128
    float* ue      = w + 128;           // 65536
    float* qz      = ue + 65536;        // 65536
    float* exbuf   = qz + 65536;        // 65536
    float* rowsum  = exbuf + 65536;     // 512
    float* g1      = rowsum + 512;      // 65536
    float* g2      = g1 + 65536;        // 65536
    float* Tt      = g2 + 65536;        // 262144
    float* U2      = Tt + 262144;       // 1048576 (fp32, qhnF input)
    float* prs     = U2 + 1048576;      // 25600 (partial row-sums [50][512])
    unsigned short* qzb  = (unsigned short*)(prs + 25600);   // 65536
    unsigned short* Ebf  = qzb + 65536;                      // 4,096,000
    unsigned short* Etf  = Ebf + 4096000;                    // 4,096,000
    unsigned short* A0b  = Etf + 4096000;                    // 524288
    unsigned short* A1b  = A0b + 524288;                     // 524288
    unsigned short* A0Tb = A1b + 524288;                     // 524288
    unsigned short* A1Tb = A0Tb + 524288;                    // 524288
    unsigned short* Ut   = A1Tb + 524288;                    // 1048576
    unsigned short* Wt   = Ut + 1048576;                     // 1048576
    int* rowidx = (int*)(Wt + 1048576);                      // 512
    int* nactb  = rowidx + 512;                              // 16

    // partial exbuf slabs [50][512][128] f32 = 13.1 MB, live only between
    // fusedA and fusedB -> reuse d_out (65.5 MB, dead until final msgx).
    float* partial = out;

    hipMemsetAsync(meansum, 0, 128 * sizeof(float), stream);
    prep_k<<<1382, 256, 0, stream>>>(E, Ebf, Etf, T, Tt, mmask, rowidx, nactb, meansum);
    init_k<<<512, 64, 0, stream>>>(x, mask, mmask, meansum, ue, qz, qzb);

    for (int it = 0; it < 4; ++it) {
        fusedA_k<<<it ? 2304 : 512, 256, 0, stream>>>(qz, T, Tt, U2, Ut, Wt,
                                                      qzb, Ebf, Etf, rowidx, nactb, partial, prs);
        fusedB_k<<<it ? 512 : 256, 256, 0, stream>>>(qz, U2, mask, A0b, A1b, A0Tb, A1Tb,
                                                     partial, prs, rowidx, nactb, exbuf, rowsum);
        gkern_mfma_k<<<dim3(256, 2), 64, 0, stream>>>(A0b, A1b, A0Tb, A1Tb, Ut, Wt, g1, g2);
        zupd_k<<<512, 64, 0, stream>>>(ue, x, mmask, exbuf, rowsum, g1, g2, mask, qz, qzb, it ? 1 : 0);
    }
    msgx_mfma_k<<<dim3(8, 125), 256, 0, stream>>>(qzb, Ebf, out);
}

// Round 14
// 370.471 us; speedup vs baseline: 3.7887x; 1.0203x over previous
//
#include <hip/hip_runtime.h>
#include <math.h>

#define L_ 128
#define D_ 128
#define H_ 8
#define V_ 32000
#define NEGC 1e9f

typedef short short8 __attribute__((ext_vector_type(8)));
typedef float f32x4 __attribute__((ext_vector_type(4)));
typedef unsigned short ushort8v __attribute__((ext_vector_type(8)));

__device__ __forceinline__ unsigned short f2bf(float x) {
    unsigned int u = __float_as_uint(x);
    unsigned int r = (u + 0x7fff + ((u >> 16) & 1)) >> 16;
    return (unsigned short)r;
}

// ---------- one-time precompute ----------

// prep_k = frag (blocks [0,1000)) | transT ([1000,1256)) | compact (1256)
//        | colsum ([1257,1382)) — all 256 thr, independent parts.
// colsum now writes NON-atomic per-block partials cs[125][128]; init_k sums
// them (deletes the meansum memset dispatch).
__global__ __launch_bounds__(256) void prep_k(const float* __restrict__ E,
                                              unsigned short* __restrict__ Ebf,
                                              unsigned short* __restrict__ Etf,
                                              const float* __restrict__ T, float* __restrict__ Tt,
                                              const int* __restrict__ m_mask,
                                              int* __restrict__ rowidx, int* __restrict__ nactb,
                                              float* __restrict__ cs) {
    __shared__ __align__(16) unsigned char psmem[8704];
    int blk = blockIdx.x;
    int t = threadIdx.x;
    if (blk < 1000) {
        unsigned short* tile = (unsigned short*)psmem;   // [32][136]
        int v0 = blk * 32;
#pragma unroll
        for (int i = 0; i < 4; ++i) {
            int idx = i * 256 + t;
            int v = idx >> 5;
            int d4 = (idx & 31) * 4;
            float4 val = *(const float4*)&E[(size_t)(v0 + v) * 128 + d4];
            tile[v * 136 + d4 + 0] = f2bf(val.x);
            tile[v * 136 + d4 + 1] = f2bf(val.y);
            tile[v * 136 + d4 + 2] = f2bf(val.z);
            tile[v * 136 + d4 + 3] = f2bf(val.w);
        }
        __syncthreads();
        {
            int fi = t >> 5;
            int l0 = (t & 31) * 2;
            int vtl = fi >> 2, s = fi & 3;
            size_t base = ((size_t)(blk * 2 + vtl) * 4 + s) * 512;
#pragma unroll
            for (int li = 0; li < 2; ++li) {
                int l = l0 + li;
                int nl = l & 15, hf = l >> 4;
                ushort8v o;
#pragma unroll
                for (int j = 0; j < 8; ++j) o[j] = tile[(vtl * 16 + nl) * 136 + s * 32 + hf * 8 + j];
                *(ushort8v*)&Ebf[base + l * 8] = o;
            }
        }
        {
            int ct = t >> 5;
            int l0 = (t & 31) * 2;
            size_t base = ((size_t)blk * 8 + ct) * 512;
#pragma unroll
            for (int li = 0; li < 2; ++li) {
                int l = l0 + li;
                int nl = l & 15, hf = l >> 4;
                ushort8v o;
#pragma unroll
                for (int j = 0; j < 8; ++j) o[j] = tile[(hf * 8 + j) * 136 + ct * 16 + nl];
                *(ushort8v*)&Etf[base + l * 8] = o;
            }
        }
    } else if (blk < 1256) {
        int tb = blk - 1000;
        for (int q = 0; q < 4; ++q) {
            int id = tb * 1024 + q * 256 + t;
            int k = id >> 17;
            int rem = id & 131071;
            int a = rem >> 10;
            int bc = rem & 1023;
            int b = bc >> 3, c = bc & 7;
            Tt[k * 131072 + b * 1024 + a * 8 + c] = T[id];
        }
    } else if (blk == 1256) {
        // compact with 256 threads over 512 rows
        int* wc = (int*)psmem;   // [8]
        bool a0 = m_mask[t] != 0;
        bool a1 = m_mask[t + 256] != 0;
        unsigned long long b0 = __ballot(a0);
        unsigned long long b1 = __ballot(a1);
        int w = t >> 6, lane = t & 63;
        if (lane == 0) { wc[w] = __popcll(b0); wc[4 + w] = __popcll(b1); }
        __syncthreads();
        int base0 = 0;
        for (int i = 0; i < w; ++i) base0 += wc[i];
        int base1 = 0;
        for (int i = 0; i < 4 + w; ++i) base1 += wc[i];
        if (a0) rowidx[base0 + __popcll(b0 & ((1ull << lane) - 1))] = t;
        if (a1) rowidx[base1 + __popcll(b1 & ((1ull << lane) - 1))] = t + 256;
        if (t == 0) {
            int tot = 0;
            for (int i = 0; i < 8; ++i) tot += wc[i];
            nactb[0] = tot;
        }
    } else {
        // colsum partials (non-atomic)
        float* red = (float*)psmem;   // [256]
        int pblk = blk - 1257;        // 0..124
        int d = t & 127, h = t >> 7;
        int v0 = pblk * 256;
        float s = 0.f;
        for (int p = 0; p < 128; ++p)
            s += E[(size_t)(v0 + h + 2 * p) * 128 + d];
        red[t] = s;
        __syncthreads();
        if (h == 0) cs[pblk * 128 + d] = red[d] + red[128 + d];
    }
}

// ue = select(mm, colmean, x);  qz = softmax_D(ue*keep)*keep  (+ bf16 copy)
// colmean = (sum of 125 cs partials)/32000, summed in fixed order.
__global__ __launch_bounds__(64) void init_k(const float* __restrict__ x, const int* __restrict__ mask,
                                             const int* __restrict__ m_mask, const float* __restrict__ cs,
                                             float* __restrict__ ue, float* __restrict__ qz,
                                             unsigned short* __restrict__ qzb) {
    int row = blockIdx.x, t = threadIdx.x;
    float keepv = mask[row] ? 1.f : 0.f;
    bool mm = m_mask[row] != 0;
    float s0 = 0.f, s1 = 0.f;
#pragma unroll 5
    for (int p = 0; p < 125; ++p) {
        s0 += cs[p * 128 + t];
        s1 += cs[p * 128 + t + 64];
    }
    float pre0 = s0 * (1.f / 32000.f);
    float pre1 = s1 * (1.f / 32000.f);
    float u0 = mm ? pre0 : x[row * 128 + t];
    float u1 = mm ? pre1 : x[row * 128 + t + 64];
    ue[row * 128 + t] = u0;
    ue[row * 128 + t + 64] = u1;
    float sv0 = u0 * keepv, sv1 = u1 * keepv;
    float m = fmaxf(sv0, sv1);
    for (int off = 32; off; off >>= 1) m = fmaxf(m, __shfl_xor(m, off));
    float e0 = __expf(sv0 - m), e1 = __expf(sv1 - m);
    float s = e0 + e1;
    for (int off = 32; off; off >>= 1) s += __shfl_xor(s, off);
    float inv = keepv / s;
    float q0 = e0 * inv, q1 = e1 * inv;
    qz[row * 128 + t] = q0;
    qz[row * 128 + t + 64] = q1;
    qzb[row * 128 + t] = f2bf(q0);
    qzb[row * 128 + t + 64] = f2bf(q1);
}

// ---------- per-iteration kernels ----------

// fusedA = uwgemm (blocks [0,256)) | pxe (blocks [256,2048)).  Independent parts.
// uwgemm: 2 output columns per thread — same 512 LDS reads/thread serve 2x the
// outputs, halving per-CU LDS-read bytes (the previous binding pipe). Per-output
// summation order unchanged -> bit-identical U2/Ut/Wt.
__global__ __launch_bounds__(256) void fusedA_k(const float* __restrict__ qz, const float* __restrict__ T,
                                                const float* __restrict__ Tt, float* __restrict__ U2,
                                                unsigned short* __restrict__ Ut, unsigned short* __restrict__ Wt,
                                                const unsigned short* __restrict__ qzb,
                                                const unsigned short* __restrict__ Ebf,
                                                const unsigned short* __restrict__ Etf,
                                                const int* __restrict__ rowidx, const int* __restrict__ nactb,
                                                float* __restrict__ partial, float* __restrict__ partial_rs) {
    __shared__ __align__(16) unsigned char smem[42752];
    int blk = blockIdx.x;
    int t = threadIdx.x;
    if (blk < 256) {
        // ---- uwgemm (2 cols/thread) ----
        float* aL = (float*)smem;           // [2048]
        int by = blk >> 4;                  // 16: uw(2) x z(4) x k(2)
        int uw = by >> 3, z = (by >> 1) & 3, k = by & 1;
        int bx = blk & 15;                  // 16: mt(8) x nt(2)
        int m0 = (bx >> 1) * 16;
        int n0 = (bx & 1) * 512 + t;        // this thread's columns: n0, n0+256
        const float* A = qz + z * 16384;
        const float* Bm = (uw ? Tt : T) + k * 131072;
        for (int idx = t; idx < 2048; idx += 256)
            aL[idx] = A[(m0 + (idx >> 7)) * 128 + (idx & 127)];
        __syncthreads();
        float acc0[16], acc1[16];
#pragma unroll
        for (int m = 0; m < 16; ++m) { acc0[m] = 0.f; acc1[m] = 0.f; }
        for (int kq = 0; kq < 32; ++kq) {
            float b00 = Bm[(kq * 4 + 0) * 1024 + n0];
            float b10 = Bm[(kq * 4 + 1) * 1024 + n0];
            float b20 = Bm[(kq * 4 + 2) * 1024 + n0];
            float b30 = Bm[(kq * 4 + 3) * 1024 + n0];
            float b01 = Bm[(kq * 4 + 0) * 1024 + n0 + 256];
            float b11 = Bm[(kq * 4 + 1) * 1024 + n0 + 256];
            float b21 = Bm[(kq * 4 + 2) * 1024 + n0 + 256];
            float b31 = Bm[(kq * 4 + 3) * 1024 + n0 + 256];
#pragma unroll
            for (int m = 0; m < 16; ++m) {
                const float4 aq = *(const float4*)&aL[m * 128 + kq * 4];
                acc0[m] += aq.x * b00 + aq.y * b10 + aq.z * b20 + aq.w * b30;
                acc1[m] += aq.x * b01 + aq.y * b11 + aq.z * b21 + aq.w * b31;
            }
        }
        if (uw == 0) {
            float* Cm = U2 + (z * 2 + k) * 131072;
#pragma unroll
            for (int m = 0; m < 16; ++m) {
                Cm[(m0 + m) * 1024 + n0] = acc0[m];
                Cm[(m0 + m) * 1024 + n0 + 256] = acc1[m];
            }
        }
        unsigned short* Tbase = (uw ? Wt : Ut) + (size_t)(z * 2 + k) * 131072;
        {
            int bb = n0 >> 3, cc = n0 & 7;
            ushort8v p0, p1;
#pragma unroll
            for (int m = 0; m < 8; ++m) { p0[m] = f2bf(acc0[m]); p1[m] = f2bf(acc0[8 + m]); }
            unsigned short* To = Tbase + (size_t)bb * 1024 + cc * 128 + m0;
            *(ushort8v*)&To[0] = p0;
            *(ushort8v*)&To[8] = p1;
        }
        {
            int n1 = n0 + 256;
            int bb = n1 >> 3, cc = n1 & 7;
            ushort8v p0, p1;
#pragma unroll
            for (int m = 0; m < 8; ++m) { p0[m] = f2bf(acc1[m]); p1[m] = f2bf(acc1[8 + m]); }
            unsigned short* To = Tbase + (size_t)bb * 1024 + cc * 128 + m0;
            *(ushort8v*)&To[0] = p0;
            *(ushort8v*)&To[8] = p1;
        }
    } else {
        // ---- pxe (round-5 structure, NO atomics) ----
        int nact = nactb[0];
        int bid = blk - 256;                  // 0..1791 (256%8==0: swizzle parity kept)
        int xcd = bid & 7, idx = bid >> 3;    // idx 0..223
        int g = xcd + 8 * (idx >> 5);         // v-group 0..55 (g>=50 dead)
        int bx = idx & 31;                    // row-tile
        int r0 = bx * 16;
        if (g >= 50 || r0 >= nact) return;
        unsigned short* Pl = (unsigned short*)smem;               // [4][2][576]
        float* slab = (float*)(smem + 9216);                      // [4][2080]
        float* rsW  = (float*)(smem + 9216 + 33280);              // [4][16]
        int w = t >> 6, lane = t & 63;
        int nloc = lane & 15, half = lane >> 4;
        int rA = r0 + nloc;
        bool actA = rA < nact;
        int rowA = actA ? rowidx[rA] : 0;
        short8 zero8 = (short8){0, 0, 0, 0, 0, 0, 0, 0};
        short8 afr[4];                         // qz frag (idx=z-row, k=d)
#pragma unroll
        for (int s = 0; s < 4; ++s) {
            short8 v = *(const short8*)&qzb[rowA * 128 + s * 32 + half * 8];
            afr[s] = actA ? v : zero8;
        }
        const int kc0 = g * 20 + w * 5;        // this wave's 5 chunks
        short8 ebb[2][8];                      // double-buffered Ebf frags
#pragma unroll
        for (int f = 0; f < 8; ++f)
            ebb[0][f] = *(const short8*)&Ebf[((size_t)(kc0 * 8 + f)) * 512 + lane * 8];
        f32x4 acc2[8];
#pragma unroll
        for (int ct = 0; ct < 8; ++ct) acc2[ct] = (f32x4){0.f, 0.f, 0.f, 0.f};
        float rsl = 0.f;
#pragma unroll
        for (int step = 0; step < 5; ++step) {
            const int p = step & 1;
            const int kc = kc0 + step;
            short8 et[8];                      // current Etf frags (issued early)
#pragma unroll
            for (int f = 0; f < 8; ++f)
                et[f] = *(const short8*)&Etf[((size_t)(kc * 8 + f)) * 512 + lane * 8];
            if (step < 4) {                    // prefetch next Ebf frags
#pragma unroll
                for (int f = 0; f < 8; ++f)
                    ebb[p ^ 1][f] = *(const short8*)&Ebf[((size_t)((kc + 1) * 8 + f)) * 512 + lane * 8];
            }
            // MFMA1 (swapped): D[v_local = half*4+reg][z = nloc], 2 chains
            f32x4 p0 = (f32x4){0.f, 0.f, 0.f, 0.f};
            f32x4 p1 = (f32x4){0.f, 0.f, 0.f, 0.f};
#pragma unroll
            for (int s = 0; s < 4; ++s) {
                p0 = __builtin_amdgcn_mfma_f32_16x16x32_bf16(ebb[p][s], afr[s], p0, 0, 0, 0);
                p1 = __builtin_amdgcn_mfma_f32_16x16x32_bf16(ebb[p][4 + s], afr[s], p1, 0, 0, 0);
            }
            unsigned short* pw = Pl + (w * 2 + p) * 576;
            {
                float e0 = __expf(p0[0]), e1 = __expf(p0[1]), e2 = __expf(p0[2]), e3 = __expf(p0[3]);
                rsl += (e0 + e1) + (e2 + e3);
                uint2 pk = {(unsigned)f2bf(e0) | ((unsigned)f2bf(e1) << 16),
                            (unsigned)f2bf(e2) | ((unsigned)f2bf(e3) << 16)};
                *(uint2*)&pw[nloc * 36 + half * 4] = pk;
            }
            {
                float e0 = __expf(p1[0]), e1 = __expf(p1[1]), e2 = __expf(p1[2]), e3 = __expf(p1[3]);
                rsl += (e0 + e1) + (e2 + e3);
                uint2 pk = {(unsigned)f2bf(e0) | ((unsigned)f2bf(e1) << 16),
                            (unsigned)f2bf(e2) | ((unsigned)f2bf(e3) << 16)};
                *(uint2*)&pw[nloc * 36 + 16 + half * 4] = pk;
            }
            short8 a2 = *(const short8*)&pw[nloc * 36 + half * 8];
#pragma unroll
            for (int ct = 0; ct < 8; ++ct)
                acc2[ct] = __builtin_amdgcn_mfma_f32_16x16x32_bf16(a2, et[ct], acc2[ct], 0, 0, 0);
        }
        rsl += __shfl_xor(rsl, 16);
        rsl += __shfl_xor(rsl, 32);
        if (lane < 16) rsW[w * 16 + nloc] = rsl;
#pragma unroll
        for (int ct = 0; ct < 8; ++ct)
#pragma unroll
            for (int reg = 0; reg < 4; ++reg)
                slab[w * 2080 + (half * 4 + reg) * 130 + ct * 16 + nloc] = acc2[ct][reg];
        __syncthreads();
        float* pb = partial + (size_t)g * 65536;
        for (int i = t; i < 2048; i += 256) {
            int row = i >> 7, col = i & 127;
            int rr = r0 + row;
            if (rr < nact)
                pb[rr * 128 + col] = slab[row * 130 + col] + slab[2080 + row * 130 + col]
                                   + slab[4160 + row * 130 + col] + slab[6240 + row * 130 + col];
        }
        if (t < 16) {
            int rr = r0 + t;
            if (rr < nact)
                partial_rs[g * 512 + rr] = rsW[t] + rsW[16 + t] + rsW[32 + t] + rsW[48 + t];
        }
    }
}

// fusedB = qhnF (blocks [0,256)) | reduce (blocks [256,512)); independent parts.
__global__ __launch_bounds__(256) void fusedB_k(const float* __restrict__ qz, const float* __restrict__ U2,
                                                const int* __restrict__ mask,
                                                unsigned short* __restrict__ A0b, unsigned short* __restrict__ A1b,
                                                unsigned short* __restrict__ A0Tb, unsigned short* __restrict__ A1Tb,
                                                const float* __restrict__ partial, const float* __restrict__ partial_rs,
                                                const int* __restrict__ rowidx, const int* __restrict__ nactb,
                                                float* __restrict__ exbuf, float* __restrict__ rowsum) {
    __shared__ __align__(16) unsigned char smem[23552];
    int blk = blockIdx.x;
    int t = threadIdx.x;
    if (blk >= 256) {
        // ---- reduce ----
        int nact = nactb[0];
        int idx = (blk - 256) * 256 + t;   // 0..65535
        int rr = idx >> 7, col = idx & 127;
        if (rr >= nact) return;
        float s = 0.f;
#pragma unroll 10
        for (int g = 0; g < 50; ++g)
            s += partial[(size_t)g * 65536 + rr * 128 + col];
        int row = rowidx[rr];
        exbuf[row * 128 + col] = s;
        if (col == 0) {
            float ts = 0.f;
#pragma unroll 10
            for (int g = 0; g < 50; ++g) ts += partial_rs[g * 512 + rr];
            rowsum[row] = ts;
        }
        return;
    }
    // ---- qhnF ----
    float* As = (float*)smem;                     // [2][16][36]
    float* Bs = (float*)(smem + 4608);            // [128][36]
    int* maskL = (int*)(smem + 4608 + 18432);     // [128]
    int z = blk >> 6, c = (blk >> 3) & 7, iq = blk & 7;
    int i0 = iq * 16;
    int tj = t & 15, ti = t >> 4;
    int i = i0 + ti;
    if (t < 128) maskL[t] = mask[z * 128 + t];
    float acc0[8], acc1[8];
#pragma unroll
    for (int jj = 0; jj < 8; ++jj) { acc0[jj] = 0.f; acc1[jj] = 0.f; }
    const float* U2z = U2 + (size_t)z * 262144;
    const float* qzz = qz + z * 16384;
    for (int kb = 0; kb < 4; ++kb) {
        int b0 = kb * 32;
        __syncthreads();
        for (int e = t; e < 1024; e += 256) {
            int k = e >> 9, r = e & 511, ii = r >> 5, b = r & 31;
            As[(k * 16 + ii) * 36 + b] = U2z[k * 131072 + (i0 + ii) * 1024 + (b0 + b) * 8 + c];
        }
        for (int f = t; f < 1024; f += 256) {
            int j = f >> 3, b4 = f & 7;
            int slot = b4 ^ ((j >> 3) & 7);
            *(float4*)&Bs[j * 36 + slot * 4] = *(const float4*)&qzz[j * 128 + b0 + b4 * 4];
        }
        __syncthreads();
#pragma unroll
        for (int b4 = 0; b4 < 8; ++b4) {
            float4 a0 = *(const float4*)&As[(0 * 16 + ti) * 36 + b4 * 4];
            float4 a1 = *(const float4*)&As[(1 * 16 + ti) * 36 + b4 * 4];
#pragma unroll
            for (int jj = 0; jj < 8; ++jj) {
                int j = tj * 8 + jj;
                int slot = b4 ^ ((j >> 3) & 7);
                float4 bq = *(const float4*)&Bs[j * 36 + slot * 4];
                acc0[jj] += a0.x * bq.x;
                acc0[jj] += a0.y * bq.y;
                acc0[jj] += a0.z * bq.z;
                acc0[jj] += a0.w * bq.w;
                acc1[jj] += a1.x * bq.x;
                acc1[jj] += a1.y * bq.y;
                acc1[jj] += a1.z * bq.z;
                acc1[jj] += a1.w * bq.w;
            }
        }
    }
    bool vi = maskL[i] != 0;
    float fv[8];
#pragma unroll
    for (int jj = 0; jj < 8; ++jj) {
        int j2 = tj * 8 + jj;
        float F = (j2 > i) ? acc0[jj] : acc1[jj];
        if (j2 == i) F -= NEGC;
        if (!vi || maskL[j2] == 0) F = -NEGC;
        fv[jj] = F;
    }
    float mval = fv[0];
#pragma unroll
    for (int jj = 1; jj < 8; ++jj) mval = fmaxf(mval, fv[jj]);
    for (int off = 1; off < 16; off <<= 1) mval = fmaxf(mval, __shfl_xor(mval, off));
    float ssum = 0.f;
#pragma unroll
    for (int jj = 0; jj < 8; ++jj) ssum += __expf(fv[jj] - mval);
    for (int off = 1; off < 16; off <<= 1) ssum += __shfl_xor(ssum, off);
    float inv = 1.f / ssum;
    size_t base = (size_t)(z * 8 + c) * 16384;
    ushort8v v0, v1;
    unsigned short bvv[8];
#pragma unroll
    for (int jj = 0; jj < 8; ++jj) {
        int j2 = tj * 8 + jj;
        float val = __expf(fv[jj] - mval) * inv;
        unsigned short bv = f2bf(val);
        bvv[jj] = bv;
        v0[jj] = (j2 > i) ? bv : (unsigned short)0;
        v1[jj] = (j2 < i) ? bv : (unsigned short)0;
    }
    *(ushort8v*)&A0b[base + i * 128 + tj * 8] = v0;
    *(ushort8v*)&A1b[base + i * 128 + tj * 8] = v1;
#pragma unroll
    for (int jj = 0; jj < 8; ++jj) {
        int j2 = tj * 8 + jj;
        A0Tb[base + j2 * 128 + i] = (i < j2) ? bvv[jj] : (unsigned short)0;
        A1Tb[base + j2 * 128 + i] = (i > j2) ? bvv[jj] : (unsigned short)0;
    }
}

// gkern as NT bf16 MFMA — 512 x 1-wave blocks (parallelism-preserving form).
__global__ __launch_bounds__(64) void gkern_mfma_k(const unsigned short* __restrict__ A0b,
                                                   const unsigned short* __restrict__ A1b,
                                                   const unsigned short* __restrict__ A0Tb,
                                                   const unsigned short* __restrict__ A1Tb,
                                                   const unsigned short* __restrict__ Ut,
                                                   const unsigned short* __restrict__ Wt,
                                                   float* __restrict__ g1, float* __restrict__ g2) {
    int mode = blockIdx.y;
    int bx = blockIdx.x;
    int z = bx >> 6, it = (bx >> 3) & 7, at = bx & 7;
    int lane = threadIdx.x;
    int nloc = lane & 15, half = lane >> 4;
    int i0 = it * 16, a0 = at * 16;
    const unsigned short* Am0 = (mode ? A0Tb : A0b) + (size_t)z * 131072;
    const unsigned short* Am1 = (mode ? A1Tb : A1b) + (size_t)z * 131072;
    const unsigned short* Bt = mode ? Ut : Wt;
    const unsigned short* B0 = Bt + (size_t)(z * 2 + 0) * 131072 + (size_t)(a0 + nloc) * 1024;
    const unsigned short* B1 = Bt + (size_t)(z * 2 + 1) * 131072 + (size_t)(a0 + nloc) * 1024;
    const unsigned short* Ar0 = Am0 + (size_t)(i0 + nloc) * 128;
    const unsigned short* Ar1 = Am1 + (size_t)(i0 + nloc) * 128;
    f32x4 acc = (f32x4){0.f, 0.f, 0.f, 0.f};
#pragma unroll
    for (int c = 0; c < 8; ++c) {
#pragma unroll
        for (int sb = 0; sb < 4; ++sb) {
            int s0 = sb * 32 + half * 8;
            short8 av0 = *(const short8*)&Ar0[c * 16384 + s0];
            short8 bv0 = *(const short8*)&B0[c * 128 + s0];
            acc = __builtin_amdgcn_mfma_f32_16x16x32_bf16(av0, bv0, acc, 0, 0, 0);
            short8 av1 = *(const short8*)&Ar1[c * 16384 + s0];
            short8 bv1 = *(const short8*)&B1[c * 128 + s0];
            acc = __builtin_amdgcn_mfma_f32_16x16x32_bf16(av1, bv1, acc, 0, 0, 0);
        }
    }
    float* G = mode ? g2 : g1;
#pragma unroll
    for (int reg = 0; reg < 4; ++reg)
        G[(z * 128 + i0 + half * 4 + reg) * 128 + a0 + nloc] = acc[reg];
}

// qz = softmax_D(u + g1 + g2) * keep  (+ bf16 copy)
__global__ __launch_bounds__(64) void zupd_k(const float* __restrict__ ue, const float* __restrict__ x,
                                             const int* __restrict__ m_mask,
                                             const float* __restrict__ exbuf, const float* __restrict__ rowsum,
                                             const float* __restrict__ g1, const float* __restrict__ g2,
                                             const int* __restrict__ mask,
                                             float* __restrict__ qz, unsigned short* __restrict__ qzb, int useEx) {
    int row = blockIdx.x, t = threadIdx.x;
    float keepv = mask[row] ? 1.f : 0.f;
    int b = row * 128;
    float u0, u1;
    if (useEx) {
        if (m_mask[row] != 0) {
            float rsv = rowsum[row];
            u0 = exbuf[b + t] / rsv;
            u1 = exbuf[b + t + 64] / rsv;
        } else {
            u0 = x[b + t];
            u1 = x[b + t + 64];
        }
    } else {
        u0 = ue[b + t];
        u1 = ue[b + t + 64];
    }
    float v0 = u0 + g1[b + t] + g2[b + t];
    float v1 = u1 + g1[b + t + 64] + g2[b + t + 64];
    float m = fmaxf(v0, v1);
    for (int off = 32; off; off >>= 1) m = fmaxf(m, __shfl_xor(m, off));
    float e0 = __expf(v0 - m), e1 = __expf(v1 - m);
    float s = e0 + e1;
    for (int off = 32; off; off >>= 1) s += __shfl_xor(s, off);
    float inv = keepv / s;
    float q0 = e0 * inv, q1 = e1 * inv;
    qz[b + t] = q0;
    qz[b + t + 64] = q1;
    qzb[b + t] = f2bf(q0);
    qzb[b + t + 64] = f2bf(q1);
}

// out[row][v] = sum_a qz[row][a] * E[v][a]   — bf16 MFMA NT-GEMM (final only).
__global__ __launch_bounds__(256) void msgx_mfma_k(const unsigned short* __restrict__ qzb,
                                                   const unsigned short* __restrict__ Ebf,
                                                   float* __restrict__ out) {
    int t = threadIdx.x;
    int w = t >> 6, lane = t & 63;
    int nloc = lane & 15, half = lane >> 4;
    int rt0 = blockIdx.x * 64;
    int cb0 = blockIdx.y * 256 + w * 64;
    short8 afr[4][4];
#pragma unroll
    for (int r = 0; r < 4; ++r)
#pragma unroll
        for (int s = 0; s < 4; ++s)
            afr[r][s] = *(const short8*)&qzb[(rt0 + r * 16 + nloc) * 128 + s * 32 + half * 8];
    f32x4 acc[4][4];
#pragma unroll
    for (int r = 0; r < 4; ++r)
#pragma unroll
        for (int ct = 0; ct < 4; ++ct)
            acc[r][ct] = (f32x4){0.f, 0.f, 0.f, 0.f};
#pragma unroll
    for (int ct = 0; ct < 4; ++ct) {
#pragma unroll
        for (int s = 0; s < 4; ++s) {
            short8 bfr = *(const short8*)&Ebf[(((size_t)(cb0 >> 4) + ct) * 4 + s) * 512 + lane * 8];
#pragma unroll
            for (int r = 0; r < 4; ++r)
                acc[r][ct] = __builtin_amdgcn_mfma_f32_16x16x32_bf16(afr[r][s], bfr, acc[r][ct], 0, 0, 0);
        }
    }
#pragma unroll
    for (int r = 0; r < 4; ++r)
#pragma unroll
        for (int ct = 0; ct < 4; ++ct) {
            int col = cb0 + ct * 16 + nloc;
#pragma unroll
            for (int reg = 0; reg < 4; ++reg) {
                int row = rt0 + r * 16 + half * 4 + reg;
                out[(size_t)row * V_ + col] = acc[r][ct][reg];
            }
        }
}

extern "C" void kernel_launch(void* const* d_in, const int* in_sizes, int n_in,
                              void* d_out, int out_size, void* d_ws, size_t ws_size,
                              hipStream_t stream) {
    const float* x     = (const float*)d_in[0];   // [B,L,D]
    const int*   mask  = (const int*)d_in[1];     // [B,L]
    const float* E     = (const float*)d_in[2];   // [V,D]
    const int*   mmask = (const int*)d_in[3];     // [B,L]
    const float* T     = (const float*)d_in[4];   // [2,D,D,H]
    float* out = (float*)d_out;                   // [B,L,V]

    float* w = (float*)d_ws;
    float* cs      = w;                 // 16000 (colsum partials [125][128])
    float* ue      = w + 16000;         // 65536
    float* qz      = ue + 65536;        // 65536
    float* exbuf   = qz + 65536;        // 65536
    float* rowsum  = exbuf + 65536;     // 512
    float* g1      = rowsum + 512;      // 65536
    float* g2      = g1 + 65536;        // 65536
    float* Tt      = g2 + 65536;        // 262144
    float* U2      = Tt + 262144;       // 1048576 (fp32, qhnF input)
    float* prs     = U2 + 1048576;      // 25600 (partial row-sums [50][512])
    unsigned short* qzb  = (unsigned short*)(prs + 25600);   // 65536
    unsigned short* Ebf  = qzb + 65536;                      // 4,096,000
    unsigned short* Etf  = Ebf + 4096000;                    // 4,096,000
    unsigned short* A0b  = Etf + 4096000;                    // 524288
    unsigned short* A1b  = A0b + 524288;                     // 524288
    unsigned short* A0Tb = A1b + 524288;                     // 524288
    unsigned short* A1Tb = A0Tb + 524288;                    // 524288
    unsigned short* Ut   = A1Tb + 524288;                    // 1048576
    unsigned short* Wt   = Ut + 1048576;                     // 1048576
    int* rowidx = (int*)(Wt + 1048576);                      // 512
    int* nactb  = rowidx + 512;                              // 16

    // partial exbuf slabs [50][512][128] f32 = 13.1 MB, live only between
    // fusedA and fusedB -> reuse d_out (65.5 MB, dead until final msgx).
    float* partial = out;

    prep_k<<<1382, 256, 0, stream>>>(E, Ebf, Etf, T, Tt, mmask, rowidx, nactb, cs);
    init_k<<<512, 64, 0, stream>>>(x, mask, mmask, cs, ue, qz, qzb);

    for (int it = 0; it < 4; ++it) {
        fusedA_k<<<it ? 2048 : 256, 256, 0, stream>>>(qz, T, Tt, U2, Ut, Wt,
                                                      qzb, Ebf, Etf, rowidx, nactb, partial, prs);
        fusedB_k<<<it ? 512 : 256, 256, 0, stream>>>(qz, U2, mask, A0b, A1b, A0Tb, A1Tb,
                                                     partial, prs, rowidx, nactb, exbuf, rowsum);
        gkern_mfma_k<<<dim3(256, 2), 64, 0, stream>>>(A0b, A1b, A0Tb, A1Tb, Ut, Wt, g1, g2);
        zupd_k<<<512, 64, 0, stream>>>(ue, x, mmask, exbuf, rowsum, g1, g2, mask, qz, qzb, it ? 1 : 0);
    }
    msgx_mfma_k<<<dim3(8, 125), 256, 0, stream>>>(qzb, Ebf, out);
}